// Round 8
// baseline (288.728 us; speedup 1.0000x reference)
//
#include <hip/hip_runtime.h>

typedef unsigned short u16;
typedef __attribute__((ext_vector_type(8))) short bf16x8;   // 8 bf16 in 4 VGPRs
typedef __attribute__((ext_vector_type(4))) float f32x4;
typedef __attribute__((ext_vector_type(16))) float f32x16;
typedef __attribute__((ext_vector_type(4))) int i32x4;

typedef const __attribute__((address_space(1))) void gvoid_t;
typedef __attribute__((address_space(3))) void svoid_t;

// fp32 -> bf16 round-to-nearest-even
__device__ __forceinline__ u16 f2bf(float f) {
  unsigned u = __builtin_bit_cast(unsigned, f);
  u += 0x7fffu + ((u >> 16) & 1u);
  return (u16)(u >> 16);
}

// packed f32 pair -> 2xbf16 in one u32 (lo=a, hi=b)
__device__ __forceinline__ unsigned cvtpk(float a, float b) {
  unsigned r;
  asm("v_cvt_pk_bf16_f32 %0, %1, %2" : "=v"(r) : "v"(a), "v"(b));
  return r;
}

// async global->LDS, 16B per lane; lds base wave-uniform (HW adds lane*16)
__device__ __forceinline__ void gload_lds16(const u16* g, u16* ldsbase) {
  __builtin_amdgcn_global_load_lds((gvoid_t*)g, (svoid_t*)ldsbase, 16, 0, 0);
}

__device__ __forceinline__ void mfma16(f32x4& d, bf16x8 a, bf16x8 b) {
  asm("v_mfma_f32_16x16x32_bf16 %0, %1, %2, %0" : "+v"(d) : "v"(a), "v"(b));
}
__device__ __forceinline__ void mfma32(f32x16& d, bf16x8 a, bf16x8 b) {
  asm("v_mfma_f32_32x32x16_bf16 %0, %1, %2, %0" : "+v"(d) : "v"(a), "v"(b));
}
__device__ __forceinline__ void mfma_fence4(f32x4& a, f32x4& b, f32x4& c, f32x4& d) {
  asm volatile("s_nop 7\n\ts_nop 7" : "+v"(a), "+v"(b), "+v"(c), "+v"(d));
}
__device__ __forceinline__ void fence16x2(f32x16& a, f32x16& b) {
  asm volatile("s_nop 7\n\ts_nop 7\n\ts_nop 7" : "+v"(a), "+v"(b));
}

// ---------------- conversions (x + all 8 weights, one launch) ----------------
struct W8 { const float* s[8]; };
__global__ __launch_bounds__(256) void cvt_all_kernel(const float* __restrict__ x,
                                                      W8 w, u16* __restrict__ xb,
                                                      u16* __restrict__ wb) {
  const int b = blockIdx.x;
  const float* src;
  u16* dst;
  int i;
  if (b < 8192) {                    // x: 8192*1024 elems
    src = x; dst = xb;
    i = (b * 256 + (int)threadIdx.x) * 4;
  } else {                           // weights: 8 x 131072 elems, 128 blocks each
    const int wi = (b - 8192) >> 7;
    const int wo = (b - 8192) & 127;
    src = w.s[wi]; dst = wb + (size_t)wi * 131072;
    i = (wo * 256 + (int)threadIdx.x) * 4;
  }
  float4 v = *(const float4*)(src + i);
  ushort4 o = {f2bf(v.x), f2bf(v.y), f2bf(v.z), f2bf(v.w)};
  *(ushort4*)(dst + i) = o;
}

// ---------------- NT GEMM: C[m][n] = sum_k A[m][k] * B[n][k] ----------------
// BM x 128 tile, BK=64, 4 waves, double-buffered XOR-swizzled LDS.
// BM=128: waves 2x2 (each 64x64, 4x4 frags). BM=64: waves 1x4 (each 64x32,
// 4x2 frags). osc[z]: output scale. vt[z]: write bf16 output transposed into
// [b*16+h][d][t=2048] layout (runtime flag, epilogue-only).
struct G3 { const u16* A[3]; const u16* B[3]; void* C[3]; float osc[3]; int vt[3]; };

template <typename OutT, int BM>
__global__ __launch_bounds__(256) void gemm_nt(G3 g, int M, int N, int K) {
  constexpr int NI = (BM == 128) ? 4 : 2;   // n-frags per wave
  __shared__ __align__(16) u16 At[2][BM * 64];
  __shared__ __align__(16) u16 Bt[2][128 * 64];
  const int z = blockIdx.z;
  const u16* __restrict__ A = g.A[z];
  const u16* __restrict__ Bw = g.B[z];
  const float osc = g.osc[z];
  const int tid = threadIdx.x;
  const int lane = tid & 63, w = tid >> 6;
  const int wm = (BM == 128) ? (w >> 1) : 0;
  const int wn = (BM == 128) ? (w & 1) : w;
  constexpr int WNW = (BM == 128) ? 64 : 32;  // wave n-width
  const int l15 = lane & 15, l4 = lane >> 4;
  const int row0 = blockIdx.x * BM, col0 = blockIdx.y * 128;
  const int srow = lane >> 3;
  const int schunk = ((lane & 7) ^ srow) * 8;
  const u16* Ag = A + (size_t)(row0 + w * 8 + srow) * K + schunk;
  const u16* Bg = Bw + (size_t)(col0 + w * 8 + srow) * K + schunk;
  f32x4 acc[4][NI] = {};
  auto STAGE = [&](int k0, int buf) {
#pragma unroll
    for (int i = 0; i < BM / 32; ++i)
      gload_lds16(Ag + (size_t)i * 32 * K + k0, &At[buf][(w * 8 + i * 32) * 64]);
#pragma unroll
    for (int i = 0; i < 4; ++i)
      gload_lds16(Bg + (size_t)i * 32 * K + k0, &Bt[buf][(w * 8 + i * 32) * 64]);
  };
  STAGE(0, 0);
  asm volatile("s_waitcnt vmcnt(0)" ::: "memory");
  __syncthreads();
  const int nk = K >> 6;
  for (int t = 0; t < nk; ++t) {
    const int cur = t & 1;
    if (t + 1 < nk) STAGE((t + 1) << 6, cur ^ 1);
#pragma unroll
    for (int kk = 0; kk < 64; kk += 32) {
      bf16x8 af[4], bfr[NI];
#pragma unroll
      for (int mi = 0; mi < 4; ++mi) {
        const int r = wm * 64 + mi * 16 + l15;
        af[mi] = *(const bf16x8*)&At[cur][r * 64 + ((kk + 8 * l4) ^ ((r & 7) << 3))];
      }
#pragma unroll
      for (int ni = 0; ni < NI; ++ni) {
        const int r = wn * WNW + ni * 16 + l15;
        bfr[ni] = *(const bf16x8*)&Bt[cur][r * 64 + ((kk + 8 * l4) ^ ((r & 7) << 3))];
      }
#pragma unroll
      for (int mi = 0; mi < 4; ++mi)
#pragma unroll
        for (int ni = 0; ni < NI; ++ni) mfma16(acc[mi][ni], af[mi], bfr[ni]);
    }
    asm volatile("s_waitcnt vmcnt(0)" ::: "memory");
    __syncthreads();
  }
#pragma unroll
  for (int mi = 0; mi < 4; ++mi)
    mfma_fence4(acc[mi][0], acc[mi][NI - 1], acc[mi][0], acc[mi][NI - 1]);
  if (g.vt[z]) {
    // output element (r, c) -> VT[(r>>11)*1024 + c][r & 2047], T=2048 (bf16)
    u16* VTo = (u16*)g.C[z];
    const int bbv = row0 >> 11;
#pragma unroll
    for (int mi = 0; mi < 4; ++mi) {
      const int r = row0 + wm * 64 + mi * 16 + l4 * 4;
      const int t0 = r & 2047;
#pragma unroll
      for (int ni = 0; ni < NI; ++ni) {
        const int c = col0 + wn * WNW + ni * 16 + l15;
        ushort4 ov = {f2bf(acc[mi][ni][0] * osc), f2bf(acc[mi][ni][1] * osc),
                      f2bf(acc[mi][ni][2] * osc), f2bf(acc[mi][ni][3] * osc)};
        *(ushort4*)(VTo + ((size_t)(bbv * 1024 + c)) * 2048 + t0) = ov;
      }
    }
  } else {
    OutT* __restrict__ C = (OutT*)g.C[z];
#pragma unroll
    for (int mi = 0; mi < 4; ++mi) {
      const int r = row0 + wm * 64 + mi * 16 + l4 * 4;
#pragma unroll
      for (int ni = 0; ni < NI; ++ni) {
        const int c = col0 + wn * WNW + ni * 16 + l15;
#pragma unroll
        for (int j = 0; j < 4; ++j) {
          float v = acc[mi][ni][j] * osc;
          if constexpr (sizeof(OutT) == 2)
            ((u16*)C)[(size_t)(r + j) * N + c] = f2bf(v);
          else
            ((float*)C)[(size_t)(r + j) * N + c] = v;
        }
      }
    }
  }
}

// ---------------- causal flash attention (swapped-QK, 4 waves x 32 q) -------
// 1024 blocks x 256 thr: bh = f&63, stripe s = f>>6 -> qt via balance map
// {15,13,11,9 | 0,2,4,6 | 14,12,10,8 | 1,3,5,7}: any residency column
// {s, s+4, s+8, s+12} sums to 30 -> every CU gets ~68 kv-iters (uniform).
// launch_bounds(256,5): 5 blocks/CU -> ALL 1024 blocks resident at t=0.
// K double-buffered in LDS (16KB only); V^T fragments loaded GLOBAL->REG
// directly (per-lane row d=dt*32+l31, L2-resident) - no V LDS, no V staging.
// Q pre-scaled by SC=0.125*log2(e); unnormalized flash p = exp2(s) (no max;
// o/lrun cancels scale; masked -> exp2(-30000)=0; diag keeps lrun>0).
// s^T = mfma32(K,Q); P packed via cvt_pk + shfl_xor(32); PV = mfma32(V^T,P).
__global__ __launch_bounds__(256, 5) void attn_kernel(const u16* __restrict__ Qg,
                                                      const u16* __restrict__ Kg,
                                                      const u16* __restrict__ VTg,
                                                      u16* __restrict__ Yg) {
  __shared__ __align__(16) u16 Kt[2][64 * 64];
  const int tid = threadIdx.x;
  const int lane = tid & 63, w = tid >> 6;
  const int l31 = lane & 31, hi = lane >> 5;
  const int f = blockIdx.x;
  const int s = f >> 6;
  const int qt = (s < 4) ? 15 - 2 * s : (s < 8) ? 2 * s - 8
               : (s < 12) ? 30 - 2 * s : 2 * s - 23;
  const int bhid = f & 63;
  const int bb = bhid >> 4, h = bhid & 15;
  const size_t rb = (size_t)bb * 2048;
  const int h64 = h * 64;
  const int qb0 = qt << 7;             // 128-row q tile
  const int qg = qb0 + w * 32 + l31;   // this lane's q row
  const int qend = qb0 + w * 32 + 31;  // wave's last q row
  const u16* Kbh = Kg + rb * 1024 + h64;
  const u16* VTbh = VTg + (size_t)bhid * 64 * 2048;  // [64 d][2048 t]
  const u16* Vrow0 = VTbh + (size_t)l31 * 2048;        // d = l31
  const u16* Vrow1 = VTbh + (size_t)(32 + l31) * 2048; // d = 32+l31
  const int srow = lane >> 3;
  const int schunk = ((lane & 7) ^ srow) * 8;

  // Q frags (B-operand): elem e of qf[kd] = Q[qg][kd*16 + 8*hi + e]
  bf16x8 qf[4];
#pragma unroll
  for (int kd = 0; kd < 4; ++kd)
    qf[kd] = *(const bf16x8*)(Qg + (rb + qg) * 1024 + h64 + kd * 16 + 8 * hi);

  f32x16 o0 = {}, o1 = {};               // o^T: d rows (+0/+32), q = l31
  const float MNEG = -30000.f;           // bounded sentinel; exp2 -> 0
  float lrun = 0.f;

  auto STAGE = [&](int it, int buf) {    // K only: wave stages rows [16w,16w+16)
    const int kv0 = it << 6;
    const int r0 = w * 16;
#pragma unroll
    for (int i = 0; i < 2; ++i)
      gload_lds16(Kbh + (size_t)(kv0 + r0 + i * 8 + srow) * 1024 + schunk,
                  &Kt[buf][(r0 + i * 8) * 64]);
  };
  STAGE(0, 0);
  asm volatile("s_waitcnt vmcnt(0)" ::: "memory");
  __syncthreads();

  const int nkv = 2 * qt + 2;
  for (int t = 0; t < nkv; ++t) {
    const int cur = t & 1;
    if (t + 1 < nkv) STAGE(t + 1, cur ^ 1);
    const int kv0 = t << 6;
    if (kv0 <= qend) {
      // ---- QK^T (s in log2 domain; Q pre-scaled)
      f32x16 s0 = {}, s1 = {};
      __builtin_amdgcn_s_setprio(1);
#pragma unroll
      for (int kd = 0; kd < 4; ++kd) {
        const int col = (kd * 16 + 8 * hi) ^ ((l31 & 7) << 3);
        bf16x8 kf0 = *(const bf16x8*)&Kt[cur][l31 * 64 + col];
        bf16x8 kf1 = *(const bf16x8*)&Kt[cur][(32 + l31) * 64 + col];
        mfma32(s0, kf0, qf[kd]);
        mfma32(s1, kf1, qf[kd]);
      }
      __builtin_amdgcn_s_setprio(0);
      // ---- V batch tl=0 issued now: latency hidden under softmax
      bf16x8 va[2][2];  // [ks][dt]
#pragma unroll
      for (int ks = 0; ks < 2; ++ks) {
        va[ks][0] = *(const bf16x8*)(Vrow0 + kv0 + ks * 16 + 8 * hi);
        va[ks][1] = *(const bf16x8*)(Vrow1 + kv0 + ks * 16 + 8 * hi);
      }
      fence16x2(s0, s1);
      // ---- causal mask (diag-band iters only; bounded sentinel)
      if (kv0 + 63 > qb0 + w * 32) {
        const int lim = qg - (kv0 + 4 * hi);
#pragma unroll
        for (int r = 0; r < 16; ++r) {
          const int C0 = (r & 3) + 8 * (r >> 2);
          if (C0 > lim) s0[r] = MNEG;
          if (C0 + 32 > lim) s1[r] = MNEG;
        }
      }
      // ---- p = exp2(s), no max-normalization (scale cancels in o/lrun)
#pragma unroll
      for (int r = 0; r < 16; ++r) {
        s0[r] = exp2f(s0[r]);
        s1[r] = exp2f(s1[r]);
      }
      // ---- row sum (explicit tree) + cross-half
      float t8[8];
#pragma unroll
      for (int r = 0; r < 8; ++r)
        t8[r] = (s0[2 * r] + s0[2 * r + 1]) + (s1[2 * r] + s1[2 * r + 1]);
      float rs = ((t8[0] + t8[1]) + (t8[2] + t8[3])) +
                 ((t8[4] + t8[5]) + (t8[6] + t8[7]));
      lrun += rs + __shfl_xor(rs, 32, 64);
      // ---- pack P into B-frags: elem e of (hi,l31) holds
      // P[q=l31][kv = tl*32 + 16ks + 8hi + e]
      i32x4 paw[4];
#pragma unroll
      for (int tl = 0; tl < 2; ++tl) {
        const f32x16& p = tl ? s1 : s0;
#pragma unroll
        for (int ks = 0; ks < 2; ++ks) {
          unsigned pk0 = cvtpk(p[8 * ks + 0], p[8 * ks + 1]);
          unsigned pk1 = cvtpk(p[8 * ks + 2], p[8 * ks + 3]);
          unsigned pk2 = cvtpk(p[8 * ks + 4], p[8 * ks + 5]);
          unsigned pk3 = cvtpk(p[8 * ks + 6], p[8 * ks + 7]);
          unsigned x0 = (unsigned)__shfl_xor((int)pk0, 32, 64);
          unsigned x1 = (unsigned)__shfl_xor((int)pk1, 32, 64);
          unsigned x2 = (unsigned)__shfl_xor((int)pk2, 32, 64);
          unsigned x3 = (unsigned)__shfl_xor((int)pk3, 32, 64);
          i32x4 A;
          A[0] = (int)(hi ? x2 : pk0);
          A[1] = (int)(hi ? x3 : pk1);
          A[2] = (int)(hi ? pk2 : x0);
          A[3] = (int)(hi ? pk3 : x1);
          paw[tl * 2 + ks] = A;
        }
      }
      // ---- V batch tl=1 issue (covered by PV tl=0 + TLP)
      bf16x8 vb[2][2];
#pragma unroll
      for (int ks = 0; ks < 2; ++ks) {
        vb[ks][0] = *(const bf16x8*)(Vrow0 + kv0 + 32 + ks * 16 + 8 * hi);
        vb[ks][1] = *(const bf16x8*)(Vrow1 + kv0 + 32 + ks * 16 + 8 * hi);
      }
      // ---- PV: o^T += V^T-frag x P-frag
      __builtin_amdgcn_s_setprio(1);
#pragma unroll
      for (int ks = 0; ks < 2; ++ks) {
        bf16x8 pa = __builtin_bit_cast(bf16x8, paw[ks]);
        mfma32(o0, va[ks][0], pa);
        mfma32(o1, va[ks][1], pa);
      }
#pragma unroll
      for (int ks = 0; ks < 2; ++ks) {
        bf16x8 pa = __builtin_bit_cast(bf16x8, paw[2 + ks]);
        mfma32(o0, vb[ks][0], pa);
        mfma32(o1, vb[ks][1], pa);
      }
      __builtin_amdgcn_s_setprio(0);
    }
    asm volatile("s_waitcnt vmcnt(0)" ::: "memory");
    __syncthreads();
  }
  fence16x2(o0, o1);
  const float inv = 1.f / lrun;
  u16* Yrow = Yg + (rb + qg) * 1024 + h64;
#pragma unroll
  for (int r = 0; r < 16; r += 2) {
    const int dbase = (r & 3) + 8 * (r >> 2) + 4 * hi;
    *(unsigned*)(Yrow + dbase) = cvtpk(o0[r] * inv, o0[r + 1] * inv);
    *(unsigned*)(Yrow + 32 + dbase) = cvtpk(o1[r] * inv, o1[r + 1] * inv);
  }
}

// ---------------- launch ----------------
extern "C" void kernel_launch(void* const* d_in, const int* in_sizes, int n_in,
                              void* d_out, int out_size, void* d_ws, size_t ws_size,
                              hipStream_t stream) {
  const float* x = (const float*)d_in[0];
  char* ws = (char*)d_ws;
  u16* xb = (u16*)ws;                          // [8192][1024] bf16 x; later attention Y
  u16* wb = (u16*)(ws + (16u << 20));          // 8 x 131072 bf16 weights
  u16* Rq = (u16*)(ws + (18u << 20));          // [8192][128]
  u16* Rk = (u16*)(ws + (20u << 20));
  u16* Rv = (u16*)(ws + (22u << 20));
  u16* Ry = (u16*)(ws + (24u << 20));
  u16* Qb = (u16*)(ws + (26u << 20));          // [8192][1024]
  u16* Kb = (u16*)(ws + (42u << 20));
  u16* VT = (u16*)(ws + (58u << 20));          // [64 bh][64 d][2048 t]
  const int WSZ = 131072;
  const float SC = 0.18033688011112042f;       // 0.125 * log2(e)

  W8 wp;
  for (int i = 0; i < 8; ++i) wp.s[i] = (const float*)d_in[1 + i];
  cvt_all_kernel<<<8192 + 1024, 256, 0, stream>>>(x, wp, xb, wb);

  // R_{q,k,v} = x @ {q,k,v}A^T   (M=8192, N=128, K=1024), BM=64 -> 384 blocks
  G3 g1;
  g1.A[0] = g1.A[1] = g1.A[2] = xb;
  g1.B[0] = wb; g1.B[1] = wb + 2 * WSZ; g1.B[2] = wb + 4 * WSZ;
  g1.C[0] = Rq; g1.C[1] = Rk; g1.C[2] = Rv;
  g1.osc[0] = g1.osc[1] = g1.osc[2] = 1.f;
  g1.vt[0] = g1.vt[1] = g1.vt[2] = 0;
  gemm_nt<u16, 64><<<dim3(128, 1, 3), 256, 0, stream>>>(g1, 8192, 128, 1024);

  // Q,K,V^T in ONE launch: Q scaled by SC; z=2 writes transposed V
  G3 g2;
  g2.A[0] = Rq; g2.A[1] = Rk; g2.A[2] = Rv;
  g2.B[0] = wb + 1 * WSZ; g2.B[1] = wb + 3 * WSZ; g2.B[2] = wb + 5 * WSZ;
  g2.C[0] = Qb; g2.C[1] = Kb; g2.C[2] = VT;
  g2.osc[0] = SC; g2.osc[1] = 1.f; g2.osc[2] = 1.f;
  g2.vt[0] = 0; g2.vt[1] = 0; g2.vt[2] = 1;
  gemm_nt<u16, 128><<<dim3(64, 8, 3), 256, 0, stream>>>(g2, 8192, 1024, 128);

  // Y (into xb) = causal attention
  attn_kernel<<<dim3(1024), 256, 0, stream>>>(Qb, Kb, VT, xb);

  // Ry = Y @ cA^T (BM=64 -> 128 blocks), out = Ry @ cB^T (fp32)
  G3 g3;
  g3.A[0] = g3.A[1] = g3.A[2] = xb;
  g3.B[0] = g3.B[1] = g3.B[2] = wb + 6 * WSZ;
  g3.C[0] = g3.C[1] = g3.C[2] = Ry;
  g3.osc[0] = g3.osc[1] = g3.osc[2] = 1.f;
  g3.vt[0] = g3.vt[1] = g3.vt[2] = 0;
  gemm_nt<u16, 64><<<dim3(128, 1, 1), 256, 0, stream>>>(g3, 8192, 128, 1024);
  G3 g4;
  g4.A[0] = g4.A[1] = g4.A[2] = Ry;
  g4.B[0] = g4.B[1] = g4.B[2] = wb + 7 * WSZ;
  g4.C[0] = g4.C[1] = g4.C[2] = d_out;
  g4.osc[0] = g4.osc[1] = g4.osc[2] = 1.f;
  g4.vt[0] = g4.vt[1] = g4.vt[2] = 0;
  gemm_nt<float, 128><<<dim3(64, 8, 1), 256, 0, stream>>>(g4, 8192, 1024, 128);
}

// Round 10
// 191.469 us; speedup vs baseline: 1.5080x; 1.5080x over previous
//
#include <hip/hip_runtime.h>

typedef unsigned short u16;
typedef __attribute__((ext_vector_type(8))) short bf16x8;   // 8 bf16 in 4 VGPRs
typedef __attribute__((ext_vector_type(4))) float f32x4;
typedef __attribute__((ext_vector_type(16))) float f32x16;
typedef __attribute__((ext_vector_type(4))) int i32x4;

typedef const __attribute__((address_space(1))) void gvoid_t;
typedef __attribute__((address_space(3))) void svoid_t;

// fp32 -> bf16 round-to-nearest-even
__device__ __forceinline__ u16 f2bf(float f) {
  unsigned u = __builtin_bit_cast(unsigned, f);
  u += 0x7fffu + ((u >> 16) & 1u);
  return (u16)(u >> 16);
}

// packed f32 pair -> 2xbf16 in one u32 (lo=a, hi=b)
__device__ __forceinline__ unsigned cvtpk(float a, float b) {
  unsigned r;
  asm("v_cvt_pk_bf16_f32 %0, %1, %2" : "=v"(r) : "v"(a), "v"(b));
  return r;
}

// async global->LDS, 16B per lane; lds base wave-uniform (HW adds lane*16)
__device__ __forceinline__ void gload_lds16(const u16* g, u16* ldsbase) {
  __builtin_amdgcn_global_load_lds((gvoid_t*)g, (svoid_t*)ldsbase, 16, 0, 0);
}

__device__ __forceinline__ void mfma16(f32x4& d, bf16x8 a, bf16x8 b) {
  asm("v_mfma_f32_16x16x32_bf16 %0, %1, %2, %0" : "+v"(d) : "v"(a), "v"(b));
}
__device__ __forceinline__ void mfma32(f32x16& d, bf16x8 a, bf16x8 b) {
  asm("v_mfma_f32_32x32x16_bf16 %0, %1, %2, %0" : "+v"(d) : "v"(a), "v"(b));
}
__device__ __forceinline__ void mfma_fence4(f32x4& a, f32x4& b, f32x4& c, f32x4& d) {
  asm volatile("s_nop 7\n\ts_nop 7" : "+v"(a), "+v"(b), "+v"(c), "+v"(d));
}
__device__ __forceinline__ void fence16x2(f32x16& a, f32x16& b) {
  asm volatile("s_nop 7\n\ts_nop 7\n\ts_nop 7" : "+v"(a), "+v"(b));
}

// chunk LUT: u -> (qt, it0, it1), sorted longest-first (LPT).
// qt<=7: single chunk (direct Y). qt>=8: two half chunks (partial o,l).
__constant__ int cQT[24] = {7,15,15,14,14,6,13,13,12,12,5,11,11,10,10,4,9,9,8,8,3,2,1,0};
__constant__ int cI0[24] = {0,0,16,0,15,0,0,14,0,13,0,0,12,0,11,0,0,10,0,9,0,0,0,0};
__constant__ int cI1[24] = {16,16,32,15,30,14,14,28,13,26,12,12,24,11,22,10,10,20,9,18,8,6,4,2};

// ---------------- conversions (x + all 8 weights, one launch) ----------------
struct W8 { const float* s[8]; };
__global__ __launch_bounds__(256) void cvt_all_kernel(const float* __restrict__ x,
                                                      W8 w, u16* __restrict__ xb,
                                                      u16* __restrict__ wb) {
  const int b = blockIdx.x;
  const float* src;
  u16* dst;
  int i;
  if (b < 8192) {                    // x: 8192*1024 elems
    src = x; dst = xb;
    i = (b * 256 + (int)threadIdx.x) * 4;
  } else {                           // weights: 8 x 131072 elems, 128 blocks each
    const int wi = (b - 8192) >> 7;
    const int wo = (b - 8192) & 127;
    src = w.s[wi]; dst = wb + (size_t)wi * 131072;
    i = (wo * 256 + (int)threadIdx.x) * 4;
  }
  float4 v = *(const float4*)(src + i);
  ushort4 o = {f2bf(v.x), f2bf(v.y), f2bf(v.z), f2bf(v.w)};
  *(ushort4*)(dst + i) = o;
}

// ---------------- NT GEMM: C[m][n] = sum_k A[m][k] * B[n][k] ----------------
struct G3 { const u16* A[3]; const u16* B[3]; void* C[3]; float osc[3]; int vt[3]; };

template <typename OutT, int BM>
__global__ __launch_bounds__(256) void gemm_nt(G3 g, int M, int N, int K) {
  constexpr int NI = (BM == 128) ? 4 : 2;   // n-frags per wave
  __shared__ __align__(16) u16 At[2][BM * 64];
  __shared__ __align__(16) u16 Bt[2][128 * 64];
  const int z = blockIdx.z;
  const u16* __restrict__ A = g.A[z];
  const u16* __restrict__ Bw = g.B[z];
  const float osc = g.osc[z];
  const int tid = threadIdx.x;
  const int lane = tid & 63, w = tid >> 6;
  const int wm = (BM == 128) ? (w >> 1) : 0;
  const int wn = (BM == 128) ? (w & 1) : w;
  constexpr int WNW = (BM == 128) ? 64 : 32;  // wave n-width
  const int l15 = lane & 15, l4 = lane >> 4;
  const int row0 = blockIdx.x * BM, col0 = blockIdx.y * 128;
  const int srow = lane >> 3;
  const int schunk = ((lane & 7) ^ srow) * 8;
  const u16* Ag = A + (size_t)(row0 + w * 8 + srow) * K + schunk;
  const u16* Bg = Bw + (size_t)(col0 + w * 8 + srow) * K + schunk;
  f32x4 acc[4][NI] = {};
  auto STAGE = [&](int k0, int buf) {
#pragma unroll
    for (int i = 0; i < BM / 32; ++i)
      gload_lds16(Ag + (size_t)i * 32 * K + k0, &At[buf][(w * 8 + i * 32) * 64]);
#pragma unroll
    for (int i = 0; i < 4; ++i)
      gload_lds16(Bg + (size_t)i * 32 * K + k0, &Bt[buf][(w * 8 + i * 32) * 64]);
  };
  STAGE(0, 0);
  asm volatile("s_waitcnt vmcnt(0)" ::: "memory");
  __syncthreads();
  const int nk = K >> 6;
  for (int t = 0; t < nk; ++t) {
    const int cur = t & 1;
    if (t + 1 < nk) STAGE((t + 1) << 6, cur ^ 1);
#pragma unroll
    for (int kk = 0; kk < 64; kk += 32) {
      bf16x8 af[4], bfr[NI];
#pragma unroll
      for (int mi = 0; mi < 4; ++mi) {
        const int r = wm * 64 + mi * 16 + l15;
        af[mi] = *(const bf16x8*)&At[cur][r * 64 + ((kk + 8 * l4) ^ ((r & 7) << 3))];
      }
#pragma unroll
      for (int ni = 0; ni < NI; ++ni) {
        const int r = wn * WNW + ni * 16 + l15;
        bfr[ni] = *(const bf16x8*)&Bt[cur][r * 64 + ((kk + 8 * l4) ^ ((r & 7) << 3))];
      }
#pragma unroll
      for (int mi = 0; mi < 4; ++mi)
#pragma unroll
        for (int ni = 0; ni < NI; ++ni) mfma16(acc[mi][ni], af[mi], bfr[ni]);
    }
    asm volatile("s_waitcnt vmcnt(0)" ::: "memory");
    __syncthreads();
  }
#pragma unroll
  for (int mi = 0; mi < 4; ++mi)
    mfma_fence4(acc[mi][0], acc[mi][NI - 1], acc[mi][0], acc[mi][NI - 1]);
  if (g.vt[z]) {
    // output element (r, c) -> VT[(r>>11)*1024 + c][r & 2047], T=2048 (bf16)
    u16* VTo = (u16*)g.C[z];
    const int bbv = row0 >> 11;
#pragma unroll
    for (int mi = 0; mi < 4; ++mi) {
      const int r = row0 + wm * 64 + mi * 16 + l4 * 4;
      const int t0 = r & 2047;
#pragma unroll
      for (int ni = 0; ni < NI; ++ni) {
        const int c = col0 + wn * WNW + ni * 16 + l15;
        ushort4 ov = {f2bf(acc[mi][ni][0] * osc), f2bf(acc[mi][ni][1] * osc),
                      f2bf(acc[mi][ni][2] * osc), f2bf(acc[mi][ni][3] * osc)};
        *(ushort4*)(VTo + ((size_t)(bbv * 1024 + c)) * 2048 + t0) = ov;
      }
    }
  } else {
    OutT* __restrict__ C = (OutT*)g.C[z];
#pragma unroll
    for (int mi = 0; mi < 4; ++mi) {
      const int r = row0 + wm * 64 + mi * 16 + l4 * 4;
#pragma unroll
      for (int ni = 0; ni < NI; ++ni) {
        const int c = col0 + wn * WNW + ni * 16 + l15;
#pragma unroll
        for (int j = 0; j < 4; ++j) {
          float v = acc[mi][ni][j] * osc;
          if constexpr (sizeof(OutT) == 2)
            ((u16*)C)[(size_t)(r + j) * N + c] = f2bf(v);
          else
            ((float*)C)[(size_t)(r + j) * N + c] = v;
        }
      }
    }
  }
}

// ---------------- causal flash attention (swapped-QK, 4 waves x 32 q) -------
// 1536 blocks x 256 thr: f -> bh = f&63, u = f>>6 -> (qt, it0, it1) via LUT
// (longest chunks first; qt>=8 split into 2 kv-halves). 5 blocks/CU (LDS
// 32KB x 5 = 160KB) -> ~256 pending blocks give real backfill as chunks
// retire. UNNORMALIZED flash (p = exp2(s), no row max) makes kv-partials
// same-scale -> chunks merge by pure ADDITION in merge_kernel.
// K,V^T double-buffered in LDS via gload_lds (XOR-swizzled rows).
// NOTE: buffer parity is CHUNK-RELATIVE ((t-it0)&1) — absolute parity read
// an unstaged buffer when it0 was odd (round-9 bug).
__global__ __launch_bounds__(256, 5) void attn_kernel(const u16* __restrict__ Qg,
                                                      const u16* __restrict__ Kg,
                                                      const u16* __restrict__ VTg,
                                                      u16* __restrict__ Yg,
                                                      float* __restrict__ PSo,
                                                      float* __restrict__ Ls) {
  __shared__ __align__(16) u16 Kt[2][64 * 64];
  __shared__ __align__(16) u16 Vt[2][64 * 64];
  const int tid = threadIdx.x;
  const int lane = tid & 63, w = tid >> 6;
  const int l31 = lane & 31, hi = lane >> 5;
  const int f = blockIdx.x;
  const int u = f >> 6;
  const int qt = cQT[u], it0 = cI0[u], it1 = cI1[u];
  const int bhid = f & 63;
  const int bb = bhid >> 4, h = bhid & 15;
  const size_t rb = (size_t)bb * 2048;
  const int h64 = h * 64;
  const int qb0 = qt << 7;             // 128-row q tile
  const int qg = qb0 + w * 32 + l31;   // this lane's q row
  const int qend = qb0 + w * 32 + 31;  // wave's last q row
  const u16* Kbh = Kg + rb * 1024 + h64;
  const u16* VTbh = VTg + (size_t)bhid * 64 * 2048;  // [64 d][2048 t]
  const int srow = lane >> 3;
  const int schunk = ((lane & 7) ^ srow) * 8;

  // Q frags (B-operand): elem e of qf[kd] = Q[qg][kd*16 + 8*hi + e]
  bf16x8 qf[4];
#pragma unroll
  for (int kd = 0; kd < 4; ++kd)
    qf[kd] = *(const bf16x8*)(Qg + (rb + qg) * 1024 + h64 + kd * 16 + 8 * hi);

  f32x16 o0 = {}, o1 = {};               // o^T: d rows (+0/+32), q = l31
  const float MNEG = -30000.f;           // bounded sentinel; exp2 -> 0
  float lrun = 0.f;

  auto STAGE = [&](int it, int buf) {
    const int kv0 = it << 6;
    const int r0 = w * 16;
#pragma unroll
    for (int i = 0; i < 2; ++i) {
      gload_lds16(Kbh + (size_t)(kv0 + r0 + i * 8 + srow) * 1024 + schunk,
                  &Kt[buf][(r0 + i * 8) * 64]);
      gload_lds16(VTbh + (size_t)(r0 + i * 8 + srow) * 2048 + kv0 + schunk,
                  &Vt[buf][(r0 + i * 8) * 64]);
    }
  };
  STAGE(it0, 0);
  asm volatile("s_waitcnt vmcnt(0)" ::: "memory");
  __syncthreads();

  for (int t = it0; t < it1; ++t) {
    const int cur = (t - it0) & 1;     // chunk-relative parity (bugfix)
    if (t + 1 < it1) STAGE(t + 1, cur ^ 1);
    const int kv0 = t << 6;
    if (kv0 <= qend) {
      // ---- QK^T (s in log2 domain; Q pre-scaled by 0.125*log2e)
      f32x16 s0 = {}, s1 = {};
      __builtin_amdgcn_s_setprio(1);
#pragma unroll
      for (int kd = 0; kd < 4; ++kd) {
        const int col = (kd * 16 + 8 * hi) ^ ((l31 & 7) << 3);
        bf16x8 kf0 = *(const bf16x8*)&Kt[cur][l31 * 64 + col];
        bf16x8 kf1 = *(const bf16x8*)&Kt[cur][(32 + l31) * 64 + col];
        mfma32(s0, kf0, qf[kd]);
        mfma32(s1, kf1, qf[kd]);
      }
      __builtin_amdgcn_s_setprio(0);
      fence16x2(s0, s1);
      // ---- causal mask (diag-band iters only; bounded sentinel)
      if (kv0 + 63 > qb0 + w * 32) {
        const int lim = qg - (kv0 + 4 * hi);
#pragma unroll
        for (int r = 0; r < 16; ++r) {
          const int C0 = (r & 3) + 8 * (r >> 2);
          if (C0 > lim) s0[r] = MNEG;
          if (C0 + 32 > lim) s1[r] = MNEG;
        }
      }
      // ---- p = exp2(s), no max-normalization (scale cancels in o/lrun)
#pragma unroll
      for (int r = 0; r < 16; ++r) {
        s0[r] = exp2f(s0[r]);
        s1[r] = exp2f(s1[r]);
      }
      // ---- row sum (explicit tree) + cross-half
      float t8[8];
#pragma unroll
      for (int r = 0; r < 8; ++r)
        t8[r] = (s0[2 * r] + s0[2 * r + 1]) + (s1[2 * r] + s1[2 * r + 1]);
      float rs = ((t8[0] + t8[1]) + (t8[2] + t8[3])) +
                 ((t8[4] + t8[5]) + (t8[6] + t8[7]));
      lrun += rs + __shfl_xor(rs, 32, 64);
      // ---- pack P into B-frags: elem e of (hi,l31) holds
      // P[q=l31][kv = tl*32 + 16ks + 8hi + e]
      i32x4 paw[4];
#pragma unroll
      for (int tl = 0; tl < 2; ++tl) {
        const f32x16& p = tl ? s1 : s0;
#pragma unroll
        for (int ks = 0; ks < 2; ++ks) {
          unsigned pk0 = cvtpk(p[8 * ks + 0], p[8 * ks + 1]);
          unsigned pk1 = cvtpk(p[8 * ks + 2], p[8 * ks + 3]);
          unsigned pk2 = cvtpk(p[8 * ks + 4], p[8 * ks + 5]);
          unsigned pk3 = cvtpk(p[8 * ks + 6], p[8 * ks + 7]);
          unsigned x0 = (unsigned)__shfl_xor((int)pk0, 32, 64);
          unsigned x1 = (unsigned)__shfl_xor((int)pk1, 32, 64);
          unsigned x2 = (unsigned)__shfl_xor((int)pk2, 32, 64);
          unsigned x3 = (unsigned)__shfl_xor((int)pk3, 32, 64);
          i32x4 A;
          A[0] = (int)(hi ? x2 : pk0);
          A[1] = (int)(hi ? x3 : pk1);
          A[2] = (int)(hi ? pk2 : x0);
          A[3] = (int)(hi ? pk3 : x1);
          paw[tl * 2 + ks] = A;
        }
      }
      asm volatile("s_nop 1");
      // ---- PV: o^T += V^T-frag x P-frag
      __builtin_amdgcn_s_setprio(1);
#pragma unroll
      for (int tl = 0; tl < 2; ++tl)
#pragma unroll
        for (int ks = 0; ks < 2; ++ks) {
          bf16x8 pa = __builtin_bit_cast(bf16x8, paw[tl * 2 + ks]);
          const int kvc = tl * 32 + ks * 16 + 8 * hi;
#pragma unroll
          for (int dt = 0; dt < 2; ++dt) {
            const int row = dt * 32 + l31;
            bf16x8 vf = *(const bf16x8*)&Vt[cur][row * 64 + (kvc ^ ((l31 & 7) << 3))];
            if (dt == 0) mfma32(o0, vf, pa);
            else         mfma32(o1, vf, pa);
          }
        }
      __builtin_amdgcn_s_setprio(0);
    }
    asm volatile("s_waitcnt vmcnt(0)" ::: "memory");
    __syncthreads();
  }
  fence16x2(o0, o1);
  if (qt < 8) {
    // direct: Y = o / l
    const float inv = 1.f / lrun;
    u16* Yrow = Yg + (rb + qg) * 1024 + h64;
#pragma unroll
    for (int r = 0; r < 16; r += 2) {
      const int dbase = (r & 3) + 8 * (r >> 2) + 4 * hi;
      *(unsigned*)(Yrow + dbase) = cvtpk(o0[r] * inv, o0[r + 1] * inv);
      *(unsigned*)(Yrow + 32 + dbase) = cvtpk(o1[r] * inv, o1[r + 1] * inv);
    }
  } else {
    // partial: store o (f32) and l; merged by merge_kernel (same scale: add)
    const int slot = ((((bhid << 3) | (qt - 8)) << 1) | (it0 != 0 ? 1 : 0));
    float* Po = PSo + (size_t)slot * 8192 + (size_t)(w * 32 + l31) * 64;
#pragma unroll
    for (int g = 0; g < 4; ++g) {
      // o0 r=4g..4g+3 -> d = 8g + 4hi + 0..3 (contiguous run)
      float4 v0 = {o0[4 * g + 0], o0[4 * g + 1], o0[4 * g + 2], o0[4 * g + 3]};
      float4 v1 = {o1[4 * g + 0], o1[4 * g + 1], o1[4 * g + 2], o1[4 * g + 3]};
      *(float4*)(Po + 8 * g + 4 * hi) = v0;
      *(float4*)(Po + 32 + 8 * g + 4 * hi) = v1;
    }
    if (!hi) Ls[slot * 128 + w * 32 + l31] = lrun;
  }
}

// ---------------- partial merge: Y = (o_a + o_b) / (l_a + l_b) -------------
__global__ __launch_bounds__(256) void merge_kernel(const float* __restrict__ PSo,
                                                    const float* __restrict__ Ls,
                                                    u16* __restrict__ Yg) {
  const int m = blockIdx.x * 256 + threadIdx.x;  // 512 pairs x 128 q x 16 (d/4)
  const int pair = m >> 11;
  const int rem = m & 2047;
  const int q = rem >> 4;
  const int d0 = (rem & 15) << 2;
  const int bhid = pair >> 3;
  const int qt = (pair & 7) + 8;
  const size_t s0 = (size_t)pair * 2;
  const float4 a = *(const float4*)(PSo + s0 * 8192 + q * 64 + d0);
  const float4 b = *(const float4*)(PSo + (s0 + 1) * 8192 + q * 64 + d0);
  const float inv = 1.f / (Ls[s0 * 128 + q] + Ls[(s0 + 1) * 128 + q]);
  u16* dst = Yg + ((size_t)(bhid >> 4) * 2048 + qt * 128 + q) * 1024 + (bhid & 15) * 64 + d0;
  *(unsigned*)(dst) = cvtpk((a.x + b.x) * inv, (a.y + b.y) * inv);
  *(unsigned*)(dst + 2) = cvtpk((a.z + b.z) * inv, (a.w + b.w) * inv);
}

// ---------------- launch ----------------
extern "C" void kernel_launch(void* const* d_in, const int* in_sizes, int n_in,
                              void* d_out, int out_size, void* d_ws, size_t ws_size,
                              hipStream_t stream) {
  const float* x = (const float*)d_in[0];
  char* ws = (char*)d_ws;
  u16* xb = (u16*)ws;                          // [8192][1024] bf16 x; later attention Y
  u16* wb = (u16*)(ws + (16u << 20));          // 8 x 131072 bf16 weights
  u16* Rq = (u16*)(ws + (18u << 20));          // [8192][128]; later attn lsums
  u16* Rk = (u16*)(ws + (20u << 20));
  u16* Rv = (u16*)(ws + (22u << 20));
  u16* Ry = (u16*)(ws + (24u << 20));
  u16* Qb = (u16*)(ws + (26u << 20));          // [8192][1024]
  u16* Kb = (u16*)(ws + (42u << 20));
  u16* VT = (u16*)(ws + (58u << 20));          // [64 bh][64 d][2048 t]
  float* Ls = (float*)(ws + (18u << 20));      // [1024][128] f32 partial lsums
  float* PSo = (float*)d_out;                  // partial o: 1024 x 8192 f32 = 33.5MB
  const int WSZ = 131072;
  const float SC = 0.18033688011112042f;       // 0.125 * log2(e)

  W8 wp;
  for (int i = 0; i < 8; ++i) wp.s[i] = (const float*)d_in[1 + i];
  cvt_all_kernel<<<8192 + 1024, 256, 0, stream>>>(x, wp, xb, wb);

  // R_{q,k,v} = x @ {q,k,v}A^T   (M=8192, N=128, K=1024), BM=64 -> 384 blocks
  G3 g1;
  g1.A[0] = g1.A[1] = g1.A[2] = xb;
  g1.B[0] = wb; g1.B[1] = wb + 2 * WSZ; g1.B[2] = wb + 4 * WSZ;
  g1.C[0] = Rq; g1.C[1] = Rk; g1.C[2] = Rv;
  g1.osc[0] = g1.osc[1] = g1.osc[2] = 1.f;
  g1.vt[0] = g1.vt[1] = g1.vt[2] = 0;
  gemm_nt<u16, 64><<<dim3(128, 1, 3), 256, 0, stream>>>(g1, 8192, 128, 1024);

  // Q,K,V^T in ONE launch: Q scaled by SC; z=2 writes transposed V
  G3 g2;
  g2.A[0] = Rq; g2.A[1] = Rk; g2.A[2] = Rv;
  g2.B[0] = wb + 1 * WSZ; g2.B[1] = wb + 3 * WSZ; g2.B[2] = wb + 5 * WSZ;
  g2.C[0] = Qb; g2.C[1] = Kb; g2.C[2] = VT;
  g2.osc[0] = SC; g2.osc[1] = 1.f; g2.osc[2] = 1.f;
  g2.vt[0] = 0; g2.vt[1] = 0; g2.vt[2] = 1;
  gemm_nt<u16, 128><<<dim3(64, 8, 3), 256, 0, stream>>>(g2, 8192, 1024, 128);

  // Y (into xb) = causal attention; qt>=8 split into 2 kv-chunks -> partials
  // in d_out (dead until g4) + Ls (dead Rq area), merged by merge_kernel.
  attn_kernel<<<dim3(1536), 256, 0, stream>>>(Qb, Kb, VT, xb, PSo, Ls);
  merge_kernel<<<dim3(4096), 256, 0, stream>>>(PSo, Ls, xb);

  // Ry = Y @ cA^T (BM=64 -> 128 blocks), out = Ry @ cB^T (fp32)
  G3 g3;
  g3.A[0] = g3.A[1] = g3.A[2] = xb;
  g3.B[0] = g3.B[1] = g3.B[2] = wb + 6 * WSZ;
  g3.C[0] = g3.C[1] = g3.C[2] = Ry;
  g3.osc[0] = g3.osc[1] = g3.osc[2] = 1.f;
  g3.vt[0] = g3.vt[1] = g3.vt[2] = 0;
  gemm_nt<u16, 64><<<dim3(128, 1, 1), 256, 0, stream>>>(g3, 8192, 128, 1024);
  G3 g4;
  g4.A[0] = g4.A[1] = g4.A[2] = Ry;
  g4.B[0] = g4.B[1] = g4.B[2] = wb + 7 * WSZ;
  g4.C[0] = g4.C[1] = g4.C[2] = d_out;
  g4.osc[0] = g4.osc[1] = g4.osc[2] = 1.f;
  g4.vt[0] = g4.vt[1] = g4.vt[2] = 0;
  gemm_nt<float, 128><<<dim3(64, 8, 1), 256, 0, stream>>>(g4, 8192, 1024, 128);
}

// Round 11
// 132.209 us; speedup vs baseline: 2.1839x; 1.4482x over previous
//
#include <hip/hip_runtime.h>

typedef unsigned short u16;
typedef __attribute__((ext_vector_type(8))) short bf16x8;   // 8 bf16 in 4 VGPRs
typedef __attribute__((ext_vector_type(4))) float f32x4;
typedef __attribute__((ext_vector_type(16))) float f32x16;
typedef __attribute__((ext_vector_type(4))) int i32x4;

typedef const __attribute__((address_space(1))) void gvoid_t;
typedef __attribute__((address_space(3))) void svoid_t;

// fp32 -> bf16 round-to-nearest-even
__device__ __forceinline__ u16 f2bf(float f) {
  unsigned u = __builtin_bit_cast(unsigned, f);
  u += 0x7fffu + ((u >> 16) & 1u);
  return (u16)(u >> 16);
}

// packed f32 pair -> 2xbf16 in one u32 (lo=a, hi=b)
__device__ __forceinline__ unsigned cvtpk(float a, float b) {
  unsigned r;
  asm("v_cvt_pk_bf16_f32 %0, %1, %2" : "=v"(r) : "v"(a), "v"(b));
  return r;
}

// async global->LDS, 16B per lane; lds base wave-uniform (HW adds lane*16)
__device__ __forceinline__ void gload_lds16(const u16* g, u16* ldsbase) {
  __builtin_amdgcn_global_load_lds((gvoid_t*)g, (svoid_t*)ldsbase, 16, 0, 0);
}

__device__ __forceinline__ void mfma16(f32x4& d, bf16x8 a, bf16x8 b) {
  asm("v_mfma_f32_16x16x32_bf16 %0, %1, %2, %0" : "+v"(d) : "v"(a), "v"(b));
}
__device__ __forceinline__ void mfma32(f32x16& d, bf16x8 a, bf16x8 b) {
  asm("v_mfma_f32_32x32x16_bf16 %0, %1, %2, %0" : "+v"(d) : "v"(a), "v"(b));
}
__device__ __forceinline__ void mfma_fence4(f32x4& a, f32x4& b, f32x4& c, f32x4& d) {
  asm volatile("s_nop 7\n\ts_nop 7" : "+v"(a), "+v"(b), "+v"(c), "+v"(d));
}
__device__ __forceinline__ void fence16x2(f32x16& a, f32x16& b) {
  asm volatile("s_nop 7\n\ts_nop 7\n\ts_nop 7" : "+v"(a), "+v"(b));
}

// ---------------- conversions (x + all 8 weights, one launch) ----------------
struct W8 { const float* s[8]; };
__global__ __launch_bounds__(256) void cvt_all_kernel(const float* __restrict__ x,
                                                      W8 w, u16* __restrict__ xb,
                                                      u16* __restrict__ wb) {
  const int b = blockIdx.x;
  const float* src;
  u16* dst;
  int i;
  if (b < 8192) {                    // x: 8192*1024 elems
    src = x; dst = xb;
    i = (b * 256 + (int)threadIdx.x) * 4;
  } else {                           // weights: 8 x 131072 elems, 128 blocks each
    const int wi = (b - 8192) >> 7;
    const int wo = (b - 8192) & 127;
    src = w.s[wi]; dst = wb + (size_t)wi * 131072;
    i = (wo * 256 + (int)threadIdx.x) * 4;
  }
  float4 v = *(const float4*)(src + i);
  ushort4 o = {f2bf(v.x), f2bf(v.y), f2bf(v.z), f2bf(v.w)};
  *(ushort4*)(dst + i) = o;
}

// ---------------- NT GEMM: C[m][n] = sum_k A[m][k] * B[n][k] ----------------
// BM x 128 tile, BK=64, 4 waves, double-buffered XOR-swizzled LDS.
// BM=128: waves 2x2 (each 64x64, 4x4 frags). BM=64: waves 1x4 (each 64x32,
// 4x2 frags). osc[z]: output scale. vt[z]: write bf16 output transposed into
// [b*16+h][d][t=2048] layout (runtime flag, epilogue-only).
struct G3 { const u16* A[3]; const u16* B[3]; void* C[3]; float osc[3]; int vt[3]; };

template <typename OutT, int BM>
__global__ __launch_bounds__(256) void gemm_nt(G3 g, int M, int N, int K) {
  constexpr int NI = (BM == 128) ? 4 : 2;   // n-frags per wave
  __shared__ __align__(16) u16 At[2][BM * 64];
  __shared__ __align__(16) u16 Bt[2][128 * 64];
  const int z = blockIdx.z;
  const u16* __restrict__ A = g.A[z];
  const u16* __restrict__ Bw = g.B[z];
  const float osc = g.osc[z];
  const int tid = threadIdx.x;
  const int lane = tid & 63, w = tid >> 6;
  const int wm = (BM == 128) ? (w >> 1) : 0;
  const int wn = (BM == 128) ? (w & 1) : w;
  constexpr int WNW = (BM == 128) ? 64 : 32;  // wave n-width
  const int l15 = lane & 15, l4 = lane >> 4;
  const int row0 = blockIdx.x * BM, col0 = blockIdx.y * 128;
  const int srow = lane >> 3;
  const int schunk = ((lane & 7) ^ srow) * 8;
  const u16* Ag = A + (size_t)(row0 + w * 8 + srow) * K + schunk;
  const u16* Bg = Bw + (size_t)(col0 + w * 8 + srow) * K + schunk;
  f32x4 acc[4][NI] = {};
  auto STAGE = [&](int k0, int buf) {
#pragma unroll
    for (int i = 0; i < BM / 32; ++i)
      gload_lds16(Ag + (size_t)i * 32 * K + k0, &At[buf][(w * 8 + i * 32) * 64]);
#pragma unroll
    for (int i = 0; i < 4; ++i)
      gload_lds16(Bg + (size_t)i * 32 * K + k0, &Bt[buf][(w * 8 + i * 32) * 64]);
  };
  STAGE(0, 0);
  asm volatile("s_waitcnt vmcnt(0)" ::: "memory");
  __syncthreads();
  const int nk = K >> 6;
  for (int t = 0; t < nk; ++t) {
    const int cur = t & 1;
    if (t + 1 < nk) STAGE((t + 1) << 6, cur ^ 1);
#pragma unroll
    for (int kk = 0; kk < 64; kk += 32) {
      bf16x8 af[4], bfr[NI];
#pragma unroll
      for (int mi = 0; mi < 4; ++mi) {
        const int r = wm * 64 + mi * 16 + l15;
        af[mi] = *(const bf16x8*)&At[cur][r * 64 + ((kk + 8 * l4) ^ ((r & 7) << 3))];
      }
#pragma unroll
      for (int ni = 0; ni < NI; ++ni) {
        const int r = wn * WNW + ni * 16 + l15;
        bfr[ni] = *(const bf16x8*)&Bt[cur][r * 64 + ((kk + 8 * l4) ^ ((r & 7) << 3))];
      }
#pragma unroll
      for (int mi = 0; mi < 4; ++mi)
#pragma unroll
        for (int ni = 0; ni < NI; ++ni) mfma16(acc[mi][ni], af[mi], bfr[ni]);
    }
    asm volatile("s_waitcnt vmcnt(0)" ::: "memory");
    __syncthreads();
  }
#pragma unroll
  for (int mi = 0; mi < 4; ++mi)
    mfma_fence4(acc[mi][0], acc[mi][NI - 1], acc[mi][0], acc[mi][NI - 1]);
  if (g.vt[z]) {
    // output element (r, c) -> VT[(r>>11)*1024 + c][r & 2047], T=2048 (bf16)
    u16* VTo = (u16*)g.C[z];
    const int bbv = row0 >> 11;
#pragma unroll
    for (int mi = 0; mi < 4; ++mi) {
      const int r = row0 + wm * 64 + mi * 16 + l4 * 4;
      const int t0 = r & 2047;
#pragma unroll
      for (int ni = 0; ni < NI; ++ni) {
        const int c = col0 + wn * WNW + ni * 16 + l15;
        ushort4 ov = {f2bf(acc[mi][ni][0] * osc), f2bf(acc[mi][ni][1] * osc),
                      f2bf(acc[mi][ni][2] * osc), f2bf(acc[mi][ni][3] * osc)};
        *(ushort4*)(VTo + ((size_t)(bbv * 1024 + c)) * 2048 + t0) = ov;
      }
    }
  } else {
    OutT* __restrict__ C = (OutT*)g.C[z];
#pragma unroll
    for (int mi = 0; mi < 4; ++mi) {
      const int r = row0 + wm * 64 + mi * 16 + l4 * 4;
#pragma unroll
      for (int ni = 0; ni < NI; ++ni) {
        const int c = col0 + wn * WNW + ni * 16 + l15;
#pragma unroll
        for (int j = 0; j < 4; ++j) {
          float v = acc[mi][ni][j] * osc;
          if constexpr (sizeof(OutT) == 2)
            ((u16*)C)[(size_t)(r + j) * N + c] = f2bf(v);
          else
            ((float*)C)[(size_t)(r + j) * N + c] = v;
        }
      }
    }
  }
}

// ---------------- causal flash attention (swapped-QK, 4 waves x 32 q) -------
// ROUND-7 STRUCTURE (known-good 79us): 1024 blocks x 256 thr, bh = f&63,
// qt = 15 - (f>>6); 4 blocks/CU resident; K,V^T double-buffered in LDS via
// gload_lds (XOR-swizzled rows). r8 (V global->reg: FETCH 27->254MB) and
// r9/10 (kv-split: partial-store stream thrashed L2, FETCH 27->161MB) both
// regressed -> reverted. THIS round's single change: exp2f -> 
// __builtin_amdgcn_exp2f (plain exp2f lowers to the OCML slow path; measured
// VALU ~1400cy/wave-iter vs ~350 static estimate -> library overhead).
// Unnormalized flash: p = exp2(s), no row max (o/lrun cancels scale; masked
// -> exp2(-30000)=0; diag keeps lrun>0). s^T = mfma32(K,Q); P packed via
// cvt_pk + shfl_xor(32) + hi-select; PV = mfma32(V^T,P).
__global__ __launch_bounds__(256, 4) void attn_kernel(const u16* __restrict__ Qg,
                                                      const u16* __restrict__ Kg,
                                                      const u16* __restrict__ VTg,
                                                      u16* __restrict__ Yg) {
  __shared__ __align__(16) u16 Kt[2][64 * 64];
  __shared__ __align__(16) u16 Vt[2][64 * 64];
  const int tid = threadIdx.x;
  const int lane = tid & 63, w = tid >> 6;
  const int l31 = lane & 31, hi = lane >> 5;
  const int f = blockIdx.x;
  const int qt = 15 - (f >> 6);
  const int bhid = f & 63;
  const int bb = bhid >> 4, h = bhid & 15;
  const size_t rb = (size_t)bb * 2048;
  const int h64 = h * 64;
  const int qb0 = qt << 7;             // 128-row q tile
  const int qg = qb0 + w * 32 + l31;   // this lane's q row
  const int qend = qb0 + w * 32 + 31;  // wave's last q row
  const u16* Kbh = Kg + rb * 1024 + h64;
  const u16* VTbh = VTg + (size_t)bhid * 64 * 2048;  // [64 d][2048 t]
  const int srow = lane >> 3;
  const int schunk = ((lane & 7) ^ srow) * 8;

  // Q frags (B-operand): elem e of qf[kd] = Q[qg][kd*16 + 8*hi + e]
  bf16x8 qf[4];
#pragma unroll
  for (int kd = 0; kd < 4; ++kd)
    qf[kd] = *(const bf16x8*)(Qg + (rb + qg) * 1024 + h64 + kd * 16 + 8 * hi);

  f32x16 o0 = {}, o1 = {};               // o^T: d rows (+0/+32), q = l31
  const float MNEG = -30000.f;           // bounded sentinel; exp2 -> 0
  float lrun = 0.f;

  auto STAGE = [&](int it, int buf) {
    const int kv0 = it << 6;
    const int r0 = w * 16;
#pragma unroll
    for (int i = 0; i < 2; ++i) {
      gload_lds16(Kbh + (size_t)(kv0 + r0 + i * 8 + srow) * 1024 + schunk,
                  &Kt[buf][(r0 + i * 8) * 64]);
      gload_lds16(VTbh + (size_t)(r0 + i * 8 + srow) * 2048 + kv0 + schunk,
                  &Vt[buf][(r0 + i * 8) * 64]);
    }
  };
  STAGE(0, 0);
  asm volatile("s_waitcnt vmcnt(0)" ::: "memory");
  __syncthreads();

  const int nkv = 2 * qt + 2;
  for (int t = 0; t < nkv; ++t) {
    const int cur = t & 1;
    if (t + 1 < nkv) STAGE(t + 1, cur ^ 1);
    const int kv0 = t << 6;
    if (kv0 <= qend) {
      // ---- QK^T (s in log2 domain; Q pre-scaled by 0.125*log2e)
      f32x16 s0 = {}, s1 = {};
      __builtin_amdgcn_s_setprio(1);
#pragma unroll
      for (int kd = 0; kd < 4; ++kd) {
        const int col = (kd * 16 + 8 * hi) ^ ((l31 & 7) << 3);
        bf16x8 kf0 = *(const bf16x8*)&Kt[cur][l31 * 64 + col];
        bf16x8 kf1 = *(const bf16x8*)&Kt[cur][(32 + l31) * 64 + col];
        mfma32(s0, kf0, qf[kd]);
        mfma32(s1, kf1, qf[kd]);
      }
      __builtin_amdgcn_s_setprio(0);
      fence16x2(s0, s1);
      // ---- causal mask (diag-band iters only; bounded sentinel)
      if (kv0 + 63 > qb0 + w * 32) {
        const int lim = qg - (kv0 + 4 * hi);
#pragma unroll
        for (int r = 0; r < 16; ++r) {
          const int C0 = (r & 3) + 8 * (r >> 2);
          if (C0 > lim) s0[r] = MNEG;
          if (C0 + 32 > lim) s1[r] = MNEG;
        }
      }
      // ---- p = exp2(s) via raw v_exp_f32 (NOT exp2f -> OCML slow path)
#pragma unroll
      for (int r = 0; r < 16; ++r) {
        s0[r] = __builtin_amdgcn_exp2f(s0[r]);
        s1[r] = __builtin_amdgcn_exp2f(s1[r]);
      }
      // ---- row sum (explicit tree) + cross-half
      float t8[8];
#pragma unroll
      for (int r = 0; r < 8; ++r)
        t8[r] = (s0[2 * r] + s0[2 * r + 1]) + (s1[2 * r] + s1[2 * r + 1]);
      float rs = ((t8[0] + t8[1]) + (t8[2] + t8[3])) +
                 ((t8[4] + t8[5]) + (t8[6] + t8[7]));
      lrun += rs + __shfl_xor(rs, 32, 64);
      // ---- pack P into B-frags: elem e of (hi,l31) holds
      // P[q=l31][kv = tl*32 + 16ks + 8hi + e]
      i32x4 paw[4];
#pragma unroll
      for (int tl = 0; tl < 2; ++tl) {
        const f32x16& p = tl ? s1 : s0;
#pragma unroll
        for (int ks = 0; ks < 2; ++ks) {
          unsigned pk0 = cvtpk(p[8 * ks + 0], p[8 * ks + 1]);
          unsigned pk1 = cvtpk(p[8 * ks + 2], p[8 * ks + 3]);
          unsigned pk2 = cvtpk(p[8 * ks + 4], p[8 * ks + 5]);
          unsigned pk3 = cvtpk(p[8 * ks + 6], p[8 * ks + 7]);
          unsigned x0 = (unsigned)__shfl_xor((int)pk0, 32, 64);
          unsigned x1 = (unsigned)__shfl_xor((int)pk1, 32, 64);
          unsigned x2 = (unsigned)__shfl_xor((int)pk2, 32, 64);
          unsigned x3 = (unsigned)__shfl_xor((int)pk3, 32, 64);
          i32x4 A;
          A[0] = (int)(hi ? x2 : pk0);
          A[1] = (int)(hi ? x3 : pk1);
          A[2] = (int)(hi ? pk2 : x0);
          A[3] = (int)(hi ? pk3 : x1);
          paw[tl * 2 + ks] = A;
        }
      }
      asm volatile("s_nop 1");
      // ---- PV: o^T += V^T-frag x P-frag
      __builtin_amdgcn_s_setprio(1);
#pragma unroll
      for (int tl = 0; tl < 2; ++tl)
#pragma unroll
        for (int ks = 0; ks < 2; ++ks) {
          bf16x8 pa = __builtin_bit_cast(bf16x8, paw[tl * 2 + ks]);
          const int kvc = tl * 32 + ks * 16 + 8 * hi;
#pragma unroll
          for (int dt = 0; dt < 2; ++dt) {
            const int row = dt * 32 + l31;
            bf16x8 vf = *(const bf16x8*)&Vt[cur][row * 64 + (kvc ^ ((l31 & 7) << 3))];
            if (dt == 0) mfma32(o0, vf, pa);
            else         mfma32(o1, vf, pa);
          }
        }
      __builtin_amdgcn_s_setprio(0);
    }
    asm volatile("s_waitcnt vmcnt(0)" ::: "memory");
    __syncthreads();
  }
  fence16x2(o0, o1);
  const float inv = 1.f / lrun;
  u16* Yrow = Yg + (rb + qg) * 1024 + h64;
#pragma unroll
  for (int r = 0; r < 16; r += 2) {
    const int dbase = (r & 3) + 8 * (r >> 2) + 4 * hi;
    *(unsigned*)(Yrow + dbase) = cvtpk(o0[r] * inv, o0[r + 1] * inv);
    *(unsigned*)(Yrow + 32 + dbase) = cvtpk(o1[r] * inv, o1[r + 1] * inv);
  }
}

// ---------------- launch ----------------
extern "C" void kernel_launch(void* const* d_in, const int* in_sizes, int n_in,
                              void* d_out, int out_size, void* d_ws, size_t ws_size,
                              hipStream_t stream) {
  const float* x = (const float*)d_in[0];
  char* ws = (char*)d_ws;
  u16* xb = (u16*)ws;                          // [8192][1024] bf16 x; later attention Y
  u16* wb = (u16*)(ws + (16u << 20));          // 8 x 131072 bf16 weights
  u16* Rq = (u16*)(ws + (18u << 20));          // [8192][128]
  u16* Rk = (u16*)(ws + (20u << 20));
  u16* Rv = (u16*)(ws + (22u << 20));
  u16* Ry = (u16*)(ws + (24u << 20));
  u16* Qb = (u16*)(ws + (26u << 20));          // [8192][1024]
  u16* Kb = (u16*)(ws + (42u << 20));
  u16* VT = (u16*)(ws + (58u << 20));          // [64 bh][64 d][2048 t]
  const int WSZ = 131072;
  const float SC = 0.18033688011112042f;       // 0.125 * log2(e)

  W8 wp;
  for (int i = 0; i < 8; ++i) wp.s[i] = (const float*)d_in[1 + i];
  cvt_all_kernel<<<8192 + 1024, 256, 0, stream>>>(x, wp, xb, wb);

  // R_{q,k,v} = x @ {q,k,v}A^T   (M=8192, N=128, K=1024), BM=64 -> 384 blocks
  G3 g1;
  g1.A[0] = g1.A[1] = g1.A[2] = xb;
  g1.B[0] = wb; g1.B[1] = wb + 2 * WSZ; g1.B[2] = wb + 4 * WSZ;
  g1.C[0] = Rq; g1.C[1] = Rk; g1.C[2] = Rv;
  g1.osc[0] = g1.osc[1] = g1.osc[2] = 1.f;
  g1.vt[0] = g1.vt[1] = g1.vt[2] = 0;
  gemm_nt<u16, 64><<<dim3(128, 1, 3), 256, 0, stream>>>(g1, 8192, 128, 1024);

  // Q,K,V^T in ONE launch: Q scaled by SC; z=2 writes transposed V
  G3 g2;
  g2.A[0] = Rq; g2.A[1] = Rk; g2.A[2] = Rv;
  g2.B[0] = wb + 1 * WSZ; g2.B[1] = wb + 3 * WSZ; g2.B[2] = wb + 5 * WSZ;
  g2.C[0] = Qb; g2.C[1] = Kb; g2.C[2] = VT;
  g2.osc[0] = SC; g2.osc[1] = 1.f; g2.osc[2] = 1.f;
  g2.vt[0] = 0; g2.vt[1] = 0; g2.vt[2] = 1;
  gemm_nt<u16, 128><<<dim3(64, 8, 3), 256, 0, stream>>>(g2, 8192, 1024, 128);

  // Y (into xb) = causal attention
  attn_kernel<<<dim3(1024), 256, 0, stream>>>(Qb, Kb, VT, xb);

  // Ry = Y @ cA^T (BM=64 -> 128 blocks), out = Ry @ cB^T (fp32)
  G3 g3;
  g3.A[0] = g3.A[1] = g3.A[2] = xb;
  g3.B[0] = g3.B[1] = g3.B[2] = wb + 6 * WSZ;
  g3.C[0] = g3.C[1] = g3.C[2] = Ry;
  g3.osc[0] = g3.osc[1] = g3.osc[2] = 1.f;
  g3.vt[0] = g3.vt[1] = g3.vt[2] = 0;
  gemm_nt<u16, 64><<<dim3(128, 1, 1), 256, 0, stream>>>(g3, 8192, 128, 1024);
  G3 g4;
  g4.A[0] = g4.A[1] = g4.A[2] = Ry;
  g4.B[0] = g4.B[1] = g4.B[2] = wb + 7 * WSZ;
  g4.C[0] = g4.C[1] = g4.C[2] = d_out;
  g4.osc[0] = g4.osc[1] = g4.osc[2] = 1.f;
  g4.vt[0] = g4.vt[1] = g4.vt[2] = 0;
  gemm_nt<float, 128><<<dim3(64, 8, 1), 256, 0, stream>>>(g4, 8192, 1024, 128);
}

// Round 13
// 131.030 us; speedup vs baseline: 2.2035x; 1.0090x over previous
//
#include <hip/hip_runtime.h>

typedef unsigned short u16;
typedef __attribute__((ext_vector_type(8))) short bf16x8;   // 8 bf16 in 4 VGPRs
typedef __attribute__((ext_vector_type(4))) float f32x4;
typedef __attribute__((ext_vector_type(16))) float f32x16;
typedef __attribute__((ext_vector_type(4))) int i32x4;

typedef const __attribute__((address_space(1))) void gvoid_t;
typedef __attribute__((address_space(3))) void svoid_t;

// fp32 -> bf16 round-to-nearest-even
__device__ __forceinline__ u16 f2bf(float f) {
  unsigned u = __builtin_bit_cast(unsigned, f);
  u += 0x7fffu + ((u >> 16) & 1u);
  return (u16)(u >> 16);
}

// packed f32 pair -> 2xbf16 in one u32 (lo=a, hi=b)
__device__ __forceinline__ unsigned cvtpk(float a, float b) {
  unsigned r;
  asm("v_cvt_pk_bf16_f32 %0, %1, %2" : "=v"(r) : "v"(a), "v"(b));
  return r;
}

// async global->LDS, 16B per lane; lds base wave-uniform (HW adds lane*16)
__device__ __forceinline__ void gload_lds16(const u16* g, u16* ldsbase) {
  __builtin_amdgcn_global_load_lds((gvoid_t*)g, (svoid_t*)ldsbase, 16, 0, 0);
}

__device__ __forceinline__ void mfma16(f32x4& d, bf16x8 a, bf16x8 b) {
  asm("v_mfma_f32_16x16x32_bf16 %0, %1, %2, %0" : "+v"(d) : "v"(a), "v"(b));
}
__device__ __forceinline__ void mfma32(f32x16& d, bf16x8 a, bf16x8 b) {
  asm("v_mfma_f32_32x32x16_bf16 %0, %1, %2, %0" : "+v"(d) : "v"(a), "v"(b));
}
__device__ __forceinline__ void mfma_fence4(f32x4& a, f32x4& b, f32x4& c, f32x4& d) {
  asm volatile("s_nop 7\n\ts_nop 7" : "+v"(a), "+v"(b), "+v"(c), "+v"(d));
}
__device__ __forceinline__ void fence16x2(f32x16& a, f32x16& b) {
  asm volatile("s_nop 7\n\ts_nop 7\n\ts_nop 7" : "+v"(a), "+v"(b));
}

// ---------------- conversions (weights only; x handled inside g1) -----------
struct W8 { const float* s[8]; };
__global__ __launch_bounds__(256) void cvt_w_kernel(W8 w, u16* __restrict__ wb) {
  const int b = blockIdx.x;
  const int wi = b >> 7;
  const int wo = b & 127;
  const float* src = w.s[wi];
  u16* dst = wb + (size_t)wi * 131072;
  int i = (wo * 256 + (int)threadIdx.x) * 4;
  float4 v = *(const float4*)(src + i);
  ushort4 o = {f2bf(v.x), f2bf(v.y), f2bf(v.z), f2bf(v.w)};
  *(ushort4*)(dst + i) = o;
}

// ---------------- NT GEMM: C[m][n] = sum_k A[m][k] * B[n][k] ----------------
// BM x 128 tile, BK=64, 4 waves, double-buffered XOR-swizzled LDS.
// BM=128: waves 2x2 (each 64x64, 4x4 frags). BM=64: waves 1x4 (each 64x32,
// 4x2 frags). osc[z]: output scale. vt[z]: write bf16 output transposed into
// [b*16+h][d][t=2048] layout. CVTA (BM=64 only): A is fp32; staging is
// reg-staged load -> cvt_pk -> ds_write (layout byte-identical to
// gload_lds16), eliminating the bf16-x roundtrip.
struct G3 { const u16* A[3]; const u16* B[3]; void* C[3]; float osc[3]; int vt[3]; };

template <typename OutT, int BM, bool CVTA>
__global__ __launch_bounds__(256) void gemm_nt(G3 g, int M, int N, int K) {
  constexpr int NI = (BM == 128) ? 4 : 2;   // n-frags per wave
  __shared__ __align__(16) u16 At[2][BM * 64];
  __shared__ __align__(16) u16 Bt[2][128 * 64];
  const int z = blockIdx.z;
  const u16* __restrict__ A = g.A[z];
  const float* __restrict__ Af = (const float*)g.A[z];
  const u16* __restrict__ Bw = g.B[z];
  const float osc = g.osc[z];
  const int tid = threadIdx.x;
  const int lane = tid & 63, w = tid >> 6;
  const int wm = (BM == 128) ? (w >> 1) : 0;
  const int wn = (BM == 128) ? (w & 1) : w;
  constexpr int WNW = (BM == 128) ? 64 : 32;  // wave n-width
  const int l15 = lane & 15, l4 = lane >> 4;
  const int row0 = blockIdx.x * BM, col0 = blockIdx.y * 128;
  const int srow = lane >> 3;
  const int schunk = ((lane & 7) ^ srow) * 8;
  const u16* Ag = A + (size_t)(row0 + w * 8 + srow) * K + schunk;
  const u16* Bg = Bw + (size_t)(col0 + w * 8 + srow) * K + schunk;
  f32x4 acc[4][NI] = {};
  float4 ax[4];  // CVTA staging regs (BM=64: 2 instrs x 2 float4)
  auto STAGEB = [&](int k0, int buf) {
#pragma unroll
    for (int i = 0; i < 4; ++i)
      gload_lds16(Bg + (size_t)i * 32 * K + k0, &Bt[buf][(w * 8 + i * 32) * 64]);
  };
  auto STAGEA_G = [&](int k0, int buf) {
#pragma unroll
    for (int i = 0; i < BM / 32; ++i)
      gload_lds16(Ag + (size_t)i * 32 * K + k0, &At[buf][(w * 8 + i * 32) * 64]);
  };
  auto LOADA = [&](int k0) {  // CVTA: issue fp32 loads (held in regs)
#pragma unroll
    for (int i = 0; i < BM / 32; ++i) {
      const float* src = Af + (size_t)(row0 + w * 8 + i * 32 + srow) * K + k0 + schunk;
      ax[2 * i] = *(const float4*)src;
      ax[2 * i + 1] = *(const float4*)(src + 4);
    }
  };
  auto WRITEA = [&](int buf) {  // CVTA: cvt + ds_write (same layout as gload)
#pragma unroll
    for (int i = 0; i < BM / 32; ++i) {
      i32x4 d;
      d[0] = (int)cvtpk(ax[2 * i].x, ax[2 * i].y);
      d[1] = (int)cvtpk(ax[2 * i].z, ax[2 * i].w);
      d[2] = (int)cvtpk(ax[2 * i + 1].x, ax[2 * i + 1].y);
      d[3] = (int)cvtpk(ax[2 * i + 1].z, ax[2 * i + 1].w);
      *(i32x4*)&At[buf][(w * 8 + i * 32 + srow) * 64 + (lane & 7) * 8] = d;
    }
  };
  if constexpr (CVTA) LOADA(0); else STAGEA_G(0, 0);
  STAGEB(0, 0);
  if constexpr (CVTA) WRITEA(0);
  asm volatile("s_waitcnt vmcnt(0)" ::: "memory");
  __syncthreads();
  const int nk = K >> 6;
  for (int t = 0; t < nk; ++t) {
    const int cur = t & 1;
    if (t + 1 < nk) {
      if constexpr (CVTA) LOADA((t + 1) << 6); else STAGEA_G((t + 1) << 6, cur ^ 1);
      STAGEB((t + 1) << 6, cur ^ 1);
    }
#pragma unroll
    for (int kk = 0; kk < 64; kk += 32) {
      bf16x8 af[4], bfr[NI];
#pragma unroll
      for (int mi = 0; mi < 4; ++mi) {
        const int r = wm * 64 + mi * 16 + l15;
        af[mi] = *(const bf16x8*)&At[cur][r * 64 + ((kk + 8 * l4) ^ ((r & 7) << 3))];
      }
#pragma unroll
      for (int ni = 0; ni < NI; ++ni) {
        const int r = wn * WNW + ni * 16 + l15;
        bfr[ni] = *(const bf16x8*)&Bt[cur][r * 64 + ((kk + 8 * l4) ^ ((r & 7) << 3))];
      }
#pragma unroll
      for (int mi = 0; mi < 4; ++mi)
#pragma unroll
        for (int ni = 0; ni < NI; ++ni) mfma16(acc[mi][ni], af[mi], bfr[ni]);
    }
    if constexpr (CVTA) { if (t + 1 < nk) WRITEA(cur ^ 1); }
    asm volatile("s_waitcnt vmcnt(0)" ::: "memory");
    __syncthreads();
  }
#pragma unroll
  for (int mi = 0; mi < 4; ++mi)
    mfma_fence4(acc[mi][0], acc[mi][NI - 1], acc[mi][0], acc[mi][NI - 1]);
  if (g.vt[z]) {
    // output element (r, c) -> VT[(r>>11)*1024 + c][r & 2047], T=2048 (bf16)
    u16* VTo = (u16*)g.C[z];
    const int bbv = row0 >> 11;
#pragma unroll
    for (int mi = 0; mi < 4; ++mi) {
      const int r = row0 + wm * 64 + mi * 16 + l4 * 4;
      const int t0 = r & 2047;
#pragma unroll
      for (int ni = 0; ni < NI; ++ni) {
        const int c = col0 + wn * WNW + ni * 16 + l15;
        ushort4 ov = {f2bf(acc[mi][ni][0] * osc), f2bf(acc[mi][ni][1] * osc),
                      f2bf(acc[mi][ni][2] * osc), f2bf(acc[mi][ni][3] * osc)};
        *(ushort4*)(VTo + ((size_t)(bbv * 1024 + c)) * 2048 + t0) = ov;
      }
    }
  } else {
    OutT* __restrict__ C = (OutT*)g.C[z];
#pragma unroll
    for (int mi = 0; mi < 4; ++mi) {
      const int r = row0 + wm * 64 + mi * 16 + l4 * 4;
#pragma unroll
      for (int ni = 0; ni < NI; ++ni) {
        const int c = col0 + wn * WNW + ni * 16 + l15;
#pragma unroll
        for (int j = 0; j < 4; ++j) {
          float v = acc[mi][ni][j] * osc;
          if constexpr (sizeof(OutT) == 2)
            ((u16*)C)[(size_t)(r + j) * N + c] = f2bf(v);
          else
            ((float*)C)[(size_t)(r + j) * N + c] = v;
        }
      }
    }
  }
}

// ---------------- causal flash attention (swapped-QK, 4 waves x 32 q) -------
// Round-11 attn EXACTLY (63us known-good, shfl_xor pack). Round-12's
// permlane32_swap pack is REVERTED: its lane-half orientation assumption
// failed on HW (absmax 5.48); this round bisects by keeping only CVTA in g1.
__global__ __launch_bounds__(256, 4) void attn_kernel(const u16* __restrict__ Qg,
                                                      const u16* __restrict__ Kg,
                                                      const u16* __restrict__ VTg,
                                                      u16* __restrict__ Yg) {
  __shared__ __align__(16) u16 Kt[2][64 * 64];
  __shared__ __align__(16) u16 Vt[2][64 * 64];
  const int tid = threadIdx.x;
  const int lane = tid & 63, w = tid >> 6;
  const int l31 = lane & 31, hi = lane >> 5;
  const int f = blockIdx.x;
  const int qt = 15 - (f >> 6);
  const int bhid = f & 63;
  const int bb = bhid >> 4, h = bhid & 15;
  const size_t rb = (size_t)bb * 2048;
  const int h64 = h * 64;
  const int qb0 = qt << 7;             // 128-row q tile
  const int qg = qb0 + w * 32 + l31;   // this lane's q row
  const int qend = qb0 + w * 32 + 31;  // wave's last q row
  const u16* Kbh = Kg + rb * 1024 + h64;
  const u16* VTbh = VTg + (size_t)bhid * 64 * 2048;  // [64 d][2048 t]
  const int srow = lane >> 3;
  const int schunk = ((lane & 7) ^ srow) * 8;

  // Q frags (B-operand): elem e of qf[kd] = Q[qg][kd*16 + 8*hi + e]
  bf16x8 qf[4];
#pragma unroll
  for (int kd = 0; kd < 4; ++kd)
    qf[kd] = *(const bf16x8*)(Qg + (rb + qg) * 1024 + h64 + kd * 16 + 8 * hi);

  f32x16 o0 = {}, o1 = {};               // o^T: d rows (+0/+32), q = l31
  const float MNEG = -30000.f;           // bounded sentinel; exp2 -> 0
  float lrun = 0.f;

  auto STAGE = [&](int it, int buf) {
    const int kv0 = it << 6;
    const int r0 = w * 16;
#pragma unroll
    for (int i = 0; i < 2; ++i) {
      gload_lds16(Kbh + (size_t)(kv0 + r0 + i * 8 + srow) * 1024 + schunk,
                  &Kt[buf][(r0 + i * 8) * 64]);
      gload_lds16(VTbh + (size_t)(r0 + i * 8 + srow) * 2048 + kv0 + schunk,
                  &Vt[buf][(r0 + i * 8) * 64]);
    }
  };
  STAGE(0, 0);
  asm volatile("s_waitcnt vmcnt(0)" ::: "memory");
  __syncthreads();

  const int nkv = 2 * qt + 2;
  for (int t = 0; t < nkv; ++t) {
    const int cur = t & 1;
    if (t + 1 < nkv) STAGE(t + 1, cur ^ 1);
    const int kv0 = t << 6;
    if (kv0 <= qend) {
      // ---- QK^T (s in log2 domain; Q pre-scaled by 0.125*log2e)
      f32x16 s0 = {}, s1 = {};
      __builtin_amdgcn_s_setprio(1);
#pragma unroll
      for (int kd = 0; kd < 4; ++kd) {
        const int col = (kd * 16 + 8 * hi) ^ ((l31 & 7) << 3);
        bf16x8 kf0 = *(const bf16x8*)&Kt[cur][l31 * 64 + col];
        bf16x8 kf1 = *(const bf16x8*)&Kt[cur][(32 + l31) * 64 + col];
        mfma32(s0, kf0, qf[kd]);
        mfma32(s1, kf1, qf[kd]);
      }
      __builtin_amdgcn_s_setprio(0);
      fence16x2(s0, s1);
      // ---- causal mask (diag-band iters only; bounded sentinel)
      if (kv0 + 63 > qb0 + w * 32) {
        const int lim = qg - (kv0 + 4 * hi);
#pragma unroll
        for (int r = 0; r < 16; ++r) {
          const int C0 = (r & 3) + 8 * (r >> 2);
          if (C0 > lim) s0[r] = MNEG;
          if (C0 + 32 > lim) s1[r] = MNEG;
        }
      }
      // ---- p = exp2(s) via raw v_exp_f32
#pragma unroll
      for (int r = 0; r < 16; ++r) {
        s0[r] = __builtin_amdgcn_exp2f(s0[r]);
        s1[r] = __builtin_amdgcn_exp2f(s1[r]);
      }
      // ---- row sum (explicit tree) + cross-half
      float t8[8];
#pragma unroll
      for (int r = 0; r < 8; ++r)
        t8[r] = (s0[2 * r] + s0[2 * r + 1]) + (s1[2 * r] + s1[2 * r + 1]);
      float rs = ((t8[0] + t8[1]) + (t8[2] + t8[3])) +
                 ((t8[4] + t8[5]) + (t8[6] + t8[7]));
      lrun += rs + __shfl_xor(rs, 32, 64);
      // ---- pack P into B-frags (proven shfl_xor + hi-select): elem e of
      // (hi,l31) holds P[q=l31][kv = tl*32 + 16ks + 8hi + e]
      i32x4 paw[4];
#pragma unroll
      for (int tl = 0; tl < 2; ++tl) {
        const f32x16& p = tl ? s1 : s0;
#pragma unroll
        for (int ks = 0; ks < 2; ++ks) {
          unsigned pk0 = cvtpk(p[8 * ks + 0], p[8 * ks + 1]);
          unsigned pk1 = cvtpk(p[8 * ks + 2], p[8 * ks + 3]);
          unsigned pk2 = cvtpk(p[8 * ks + 4], p[8 * ks + 5]);
          unsigned pk3 = cvtpk(p[8 * ks + 6], p[8 * ks + 7]);
          unsigned x0 = (unsigned)__shfl_xor((int)pk0, 32, 64);
          unsigned x1 = (unsigned)__shfl_xor((int)pk1, 32, 64);
          unsigned x2 = (unsigned)__shfl_xor((int)pk2, 32, 64);
          unsigned x3 = (unsigned)__shfl_xor((int)pk3, 32, 64);
          i32x4 A;
          A[0] = (int)(hi ? x2 : pk0);
          A[1] = (int)(hi ? x3 : pk1);
          A[2] = (int)(hi ? pk2 : x0);
          A[3] = (int)(hi ? pk3 : x1);
          paw[tl * 2 + ks] = A;
        }
      }
      asm volatile("s_nop 1");
      // ---- PV: o^T += V^T-frag x P-frag
      __builtin_amdgcn_s_setprio(1);
#pragma unroll
      for (int tl = 0; tl < 2; ++tl)
#pragma unroll
        for (int ks = 0; ks < 2; ++ks) {
          bf16x8 pa = __builtin_bit_cast(bf16x8, paw[tl * 2 + ks]);
          const int kvc = tl * 32 + ks * 16 + 8 * hi;
#pragma unroll
          for (int dt = 0; dt < 2; ++dt) {
            const int row = dt * 32 + l31;
            bf16x8 vf = *(const bf16x8*)&Vt[cur][row * 64 + (kvc ^ ((l31 & 7) << 3))];
            if (dt == 0) mfma32(o0, vf, pa);
            else         mfma32(o1, vf, pa);
          }
        }
      __builtin_amdgcn_s_setprio(0);
    }
    asm volatile("s_waitcnt vmcnt(0)" ::: "memory");
    __syncthreads();
  }
  fence16x2(o0, o1);
  const float inv = 1.f / lrun;
  u16* Yrow = Yg + (rb + qg) * 1024 + h64;
#pragma unroll
  for (int r = 0; r < 16; r += 2) {
    const int dbase = (r & 3) + 8 * (r >> 2) + 4 * hi;
    *(unsigned*)(Yrow + dbase) = cvtpk(o0[r] * inv, o0[r + 1] * inv);
    *(unsigned*)(Yrow + 32 + dbase) = cvtpk(o1[r] * inv, o1[r + 1] * inv);
  }
}

// ---------------- launch ----------------
extern "C" void kernel_launch(void* const* d_in, const int* in_sizes, int n_in,
                              void* d_out, int out_size, void* d_ws, size_t ws_size,
                              hipStream_t stream) {
  const float* x = (const float*)d_in[0];
  char* ws = (char*)d_ws;
  u16* xb = (u16*)ws;                          // attention Y (bf16)
  u16* wb = (u16*)(ws + (16u << 20));          // 8 x 131072 bf16 weights
  u16* Rq = (u16*)(ws + (18u << 20));          // [8192][128]
  u16* Rk = (u16*)(ws + (20u << 20));
  u16* Rv = (u16*)(ws + (22u << 20));
  u16* Ry = (u16*)(ws + (24u << 20));
  u16* Qb = (u16*)(ws + (26u << 20));          // [8192][1024]
  u16* Kb = (u16*)(ws + (42u << 20));
  u16* VT = (u16*)(ws + (58u << 20));          // [64 bh][64 d][2048 t]
  const int WSZ = 131072;
  const float SC = 0.18033688011112042f;       // 0.125 * log2(e)

  W8 wp;
  for (int i = 0; i < 8; ++i) wp.s[i] = (const float*)d_in[1 + i];
  cvt_w_kernel<<<1024, 256, 0, stream>>>(wp, wb);

  // R_{q,k,v} = x @ {q,k,v}A^T (M=8192, N=128, K=1024), fp32 x converted
  // in-staging (CVTA), BM=64 -> 384 blocks
  G3 g1;
  g1.A[0] = g1.A[1] = g1.A[2] = (const u16*)x;
  g1.B[0] = wb; g1.B[1] = wb + 2 * WSZ; g1.B[2] = wb + 4 * WSZ;
  g1.C[0] = Rq; g1.C[1] = Rk; g1.C[2] = Rv;
  g1.osc[0] = g1.osc[1] = g1.osc[2] = 1.f;
  g1.vt[0] = g1.vt[1] = g1.vt[2] = 0;
  gemm_nt<u16, 64, true><<<dim3(128, 1, 3), 256, 0, stream>>>(g1, 8192, 128, 1024);

  // Q,K,V^T in ONE launch: Q scaled by SC; z=2 writes transposed V
  G3 g2;
  g2.A[0] = Rq; g2.A[1] = Rk; g2.A[2] = Rv;
  g2.B[0] = wb + 1 * WSZ; g2.B[1] = wb + 3 * WSZ; g2.B[2] = wb + 5 * WSZ;
  g2.C[0] = Qb; g2.C[1] = Kb; g2.C[2] = VT;
  g2.osc[0] = SC; g2.osc[1] = 1.f; g2.osc[2] = 1.f;
  g2.vt[0] = 0; g2.vt[1] = 0; g2.vt[2] = 1;
  gemm_nt<u16, 128, false><<<dim3(64, 8, 3), 256, 0, stream>>>(g2, 8192, 1024, 128);

  // Y (into xb) = causal attention
  attn_kernel<<<dim3(1024), 256, 0, stream>>>(Qb, Kb, VT, xb);

  // Ry = Y @ cA^T (BM=64 -> 128 blocks), out = Ry @ cB^T (fp32)
  G3 g3;
  g3.A[0] = g3.A[1] = g3.A[2] = xb;
  g3.B[0] = g3.B[1] = g3.B[2] = wb + 6 * WSZ;
  g3.C[0] = g3.C[1] = g3.C[2] = Ry;
  g3.osc[0] = g3.osc[1] = g3.osc[2] = 1.f;
  g3.vt[0] = g3.vt[1] = g3.vt[2] = 0;
  gemm_nt<u16, 64, false><<<dim3(128, 1, 1), 256, 0, stream>>>(g3, 8192, 128, 1024);
  G3 g4;
  g4.A[0] = g4.A[1] = g4.A[2] = Ry;
  g4.B[0] = g4.B[1] = g4.B[2] = wb + 7 * WSZ;
  g4.C[0] = g4.C[1] = g4.C[2] = d_out;
  g4.osc[0] = g4.osc[1] = g4.osc[2] = 1.f;
  g4.vt[0] = g4.vt[1] = g4.vt[2] = 0;
  gemm_nt<float, 128, false><<<dim3(64, 8, 1), 256, 0, stream>>>(g4, 8192, 1024, 128);
}

// Round 14
// 125.958 us; speedup vs baseline: 2.2923x; 1.0403x over previous
//
#include <hip/hip_runtime.h>

typedef unsigned short u16;
typedef __attribute__((ext_vector_type(8))) short bf16x8;   // 8 bf16 in 4 VGPRs
typedef __attribute__((ext_vector_type(4))) float f32x4;
typedef __attribute__((ext_vector_type(16))) float f32x16;
typedef __attribute__((ext_vector_type(4))) int i32x4;

typedef const __attribute__((address_space(1))) void gvoid_t;
typedef __attribute__((address_space(3))) void svoid_t;

// fp32 -> bf16 round-to-nearest-even
__device__ __forceinline__ u16 f2bf(float f) {
  unsigned u = __builtin_bit_cast(unsigned, f);
  u += 0x7fffu + ((u >> 16) & 1u);
  return (u16)(u >> 16);
}

// packed f32 pair -> 2xbf16 in one u32 (lo=a, hi=b)
__device__ __forceinline__ unsigned cvtpk(float a, float b) {
  unsigned r;
  asm("v_cvt_pk_bf16_f32 %0, %1, %2" : "=v"(r) : "v"(a), "v"(b));
  return r;
}

// async global->LDS, 16B per lane; lds base wave-uniform (HW adds lane*16)
__device__ __forceinline__ void gload_lds16(const u16* g, u16* ldsbase) {
  __builtin_amdgcn_global_load_lds((gvoid_t*)g, (svoid_t*)ldsbase, 16, 0, 0);
}

__device__ __forceinline__ void mfma16(f32x4& d, bf16x8 a, bf16x8 b) {
  asm("v_mfma_f32_16x16x32_bf16 %0, %1, %2, %0" : "+v"(d) : "v"(a), "v"(b));
}
__device__ __forceinline__ void mfma32(f32x16& d, bf16x8 a, bf16x8 b) {
  asm("v_mfma_f32_32x32x16_bf16 %0, %1, %2, %0" : "+v"(d) : "v"(a), "v"(b));
}
__device__ __forceinline__ void mfma_fence4(f32x4& a, f32x4& b, f32x4& c, f32x4& d) {
  asm volatile("s_nop 7\n\ts_nop 7" : "+v"(a), "+v"(b), "+v"(c), "+v"(d));
}
__device__ __forceinline__ void fence16x2(f32x16& a, f32x16& b) {
  asm volatile("s_nop 7\n\ts_nop 7\n\ts_nop 7" : "+v"(a), "+v"(b));
}

// ---------------- conversions (weights only; x handled inside g1) -----------
struct W8 { const float* s[8]; };
__global__ __launch_bounds__(256) void cvt_w_kernel(W8 w, u16* __restrict__ wb) {
  const int b = blockIdx.x;
  const int wi = b >> 7;
  const int wo = b & 127;
  const float* src = w.s[wi];
  u16* dst = wb + (size_t)wi * 131072;
  int i = (wo * 256 + (int)threadIdx.x) * 4;
  float4 v = *(const float4*)(src + i);
  ushort4 o = {f2bf(v.x), f2bf(v.y), f2bf(v.z), f2bf(v.w)};
  *(ushort4*)(dst + i) = o;
}

// ---------------- NT GEMM: C[m][n] = sum_k A[m][k] * B[n][k] ----------------
// BM x 128 tile, BK=64, 4 waves, double-buffered XOR-swizzled LDS.
// BM=128: waves 2x2 (each 64x64, 4x4 frags). BM=64: waves 1x4 (each 64x32,
// 4x2 frags). osc[z]: output scale. vt[z]: write bf16 output transposed into
// [b*16+h][d][t=2048] layout. CVTA (BM=64 only): A is fp32; staging is
// reg-staged load -> cvt_pk -> ds_write (layout byte-identical to
// gload_lds16), eliminating the bf16-x roundtrip.
struct G3 { const u16* A[3]; const u16* B[3]; void* C[3]; float osc[3]; int vt[3]; };

template <typename OutT, int BM, bool CVTA>
__global__ __launch_bounds__(256) void gemm_nt(G3 g, int M, int N, int K) {
  constexpr int NI = (BM == 128) ? 4 : 2;   // n-frags per wave
  __shared__ __align__(16) u16 At[2][BM * 64];
  __shared__ __align__(16) u16 Bt[2][128 * 64];
  const int z = blockIdx.z;
  const u16* __restrict__ A = g.A[z];
  const float* __restrict__ Af = (const float*)g.A[z];
  const u16* __restrict__ Bw = g.B[z];
  const float osc = g.osc[z];
  const int tid = threadIdx.x;
  const int lane = tid & 63, w = tid >> 6;
  const int wm = (BM == 128) ? (w >> 1) : 0;
  const int wn = (BM == 128) ? (w & 1) : w;
  constexpr int WNW = (BM == 128) ? 64 : 32;  // wave n-width
  const int l15 = lane & 15, l4 = lane >> 4;
  const int row0 = blockIdx.x * BM, col0 = blockIdx.y * 128;
  const int srow = lane >> 3;
  const int schunk = ((lane & 7) ^ srow) * 8;
  const u16* Ag = A + (size_t)(row0 + w * 8 + srow) * K + schunk;
  const u16* Bg = Bw + (size_t)(col0 + w * 8 + srow) * K + schunk;
  f32x4 acc[4][NI] = {};
  float4 ax[4];  // CVTA staging regs (BM=64: 2 instrs x 2 float4)
  auto STAGEB = [&](int k0, int buf) {
#pragma unroll
    for (int i = 0; i < 4; ++i)
      gload_lds16(Bg + (size_t)i * 32 * K + k0, &Bt[buf][(w * 8 + i * 32) * 64]);
  };
  auto STAGEA_G = [&](int k0, int buf) {
#pragma unroll
    for (int i = 0; i < BM / 32; ++i)
      gload_lds16(Ag + (size_t)i * 32 * K + k0, &At[buf][(w * 8 + i * 32) * 64]);
  };
  auto LOADA = [&](int k0) {  // CVTA: issue fp32 loads (held in regs)
#pragma unroll
    for (int i = 0; i < BM / 32; ++i) {
      const float* src = Af + (size_t)(row0 + w * 8 + i * 32 + srow) * K + k0 + schunk;
      ax[2 * i] = *(const float4*)src;
      ax[2 * i + 1] = *(const float4*)(src + 4);
    }
  };
  auto WRITEA = [&](int buf) {  // CVTA: cvt + ds_write (same layout as gload)
#pragma unroll
    for (int i = 0; i < BM / 32; ++i) {
      i32x4 d;
      d[0] = (int)cvtpk(ax[2 * i].x, ax[2 * i].y);
      d[1] = (int)cvtpk(ax[2 * i].z, ax[2 * i].w);
      d[2] = (int)cvtpk(ax[2 * i + 1].x, ax[2 * i + 1].y);
      d[3] = (int)cvtpk(ax[2 * i + 1].z, ax[2 * i + 1].w);
      *(i32x4*)&At[buf][(w * 8 + i * 32 + srow) * 64 + (lane & 7) * 8] = d;
    }
  };
  if constexpr (CVTA) LOADA(0); else STAGEA_G(0, 0);
  STAGEB(0, 0);
  if constexpr (CVTA) WRITEA(0);
  asm volatile("s_waitcnt vmcnt(0)" ::: "memory");
  __syncthreads();
  const int nk = K >> 6;
  for (int t = 0; t < nk; ++t) {
    const int cur = t & 1;
    if (t + 1 < nk) {
      if constexpr (CVTA) LOADA((t + 1) << 6); else STAGEA_G((t + 1) << 6, cur ^ 1);
      STAGEB((t + 1) << 6, cur ^ 1);
    }
#pragma unroll
    for (int kk = 0; kk < 64; kk += 32) {
      bf16x8 af[4], bfr[NI];
#pragma unroll
      for (int mi = 0; mi < 4; ++mi) {
        const int r = wm * 64 + mi * 16 + l15;
        af[mi] = *(const bf16x8*)&At[cur][r * 64 + ((kk + 8 * l4) ^ ((r & 7) << 3))];
      }
#pragma unroll
      for (int ni = 0; ni < NI; ++ni) {
        const int r = wn * WNW + ni * 16 + l15;
        bfr[ni] = *(const bf16x8*)&Bt[cur][r * 64 + ((kk + 8 * l4) ^ ((r & 7) << 3))];
      }
#pragma unroll
      for (int mi = 0; mi < 4; ++mi)
#pragma unroll
        for (int ni = 0; ni < NI; ++ni) mfma16(acc[mi][ni], af[mi], bfr[ni]);
    }
    if constexpr (CVTA) { if (t + 1 < nk) WRITEA(cur ^ 1); }
    asm volatile("s_waitcnt vmcnt(0)" ::: "memory");
    __syncthreads();
  }
#pragma unroll
  for (int mi = 0; mi < 4; ++mi)
    mfma_fence4(acc[mi][0], acc[mi][NI - 1], acc[mi][0], acc[mi][NI - 1]);
  if (g.vt[z]) {
    // output element (r, c) -> VT[(r>>11)*1024 + c][r & 2047], T=2048 (bf16)
    u16* VTo = (u16*)g.C[z];
    const int bbv = row0 >> 11;
#pragma unroll
    for (int mi = 0; mi < 4; ++mi) {
      const int r = row0 + wm * 64 + mi * 16 + l4 * 4;
      const int t0 = r & 2047;
#pragma unroll
      for (int ni = 0; ni < NI; ++ni) {
        const int c = col0 + wn * WNW + ni * 16 + l15;
        ushort4 ov = {f2bf(acc[mi][ni][0] * osc), f2bf(acc[mi][ni][1] * osc),
                      f2bf(acc[mi][ni][2] * osc), f2bf(acc[mi][ni][3] * osc)};
        *(ushort4*)(VTo + ((size_t)(bbv * 1024 + c)) * 2048 + t0) = ov;
      }
    }
  } else {
    OutT* __restrict__ C = (OutT*)g.C[z];
#pragma unroll
    for (int mi = 0; mi < 4; ++mi) {
      const int r = row0 + wm * 64 + mi * 16 + l4 * 4;
#pragma unroll
      for (int ni = 0; ni < NI; ++ni) {
        const int c = col0 + wn * WNW + ni * 16 + l15;
#pragma unroll
        for (int j = 0; j < 4; ++j) {
          float v = acc[mi][ni][j] * osc;
          if constexpr (sizeof(OutT) == 2)
            ((u16*)C)[(size_t)(r + j) * N + c] = f2bf(v);
          else
            ((float*)C)[(size_t)(r + j) * N + c] = v;
        }
      }
    }
  }
}

// ---------------- causal flash attention (swapped-QK, 4 waves x 32 q) -------
// Round-13 attn with TWO independent changes:
// (1) balanced qt map {15,13,11,9 | 0,2,4,6 | 14,12,10,8 | 1,3,5,7}: every
//     CU residency column {s,s+4,s+8,s+12} sums to 30 qt = 68 iters
//     (old LPT map had 56..80 spread). Bijective -> cannot affect output.
// (2) P-pack via v_permlane32_swap_b32 with FLIPPED operand order vs the
//     failed r12 guess: swap(pk0,pk2) under mirror semantics d.hi<->s.lo
//     gives pk0 = A[0] (lo: own {0,1}; hi: partner pk2 = {8,9}) and
//     pk2 = A[2] (lo: partner pk0 = {4,5}; hi: own {12,13}).
//     A correctness failure this round uniquely convicts (2).
__global__ __launch_bounds__(256, 4) void attn_kernel(const u16* __restrict__ Qg,
                                                      const u16* __restrict__ Kg,
                                                      const u16* __restrict__ VTg,
                                                      u16* __restrict__ Yg) {
  __shared__ __align__(16) u16 Kt[2][64 * 64];
  __shared__ __align__(16) u16 Vt[2][64 * 64];
  const int tid = threadIdx.x;
  const int lane = tid & 63, w = tid >> 6;
  const int l31 = lane & 31, hi = lane >> 5;
  const int f = blockIdx.x;
  const int s = f >> 6;
  const int qt = (s < 4) ? 15 - 2 * s : (s < 8) ? 2 * s - 8
               : (s < 12) ? 30 - 2 * s : 2 * s - 23;
  const int bhid = f & 63;
  const int bb = bhid >> 4, h = bhid & 15;
  const size_t rb = (size_t)bb * 2048;
  const int h64 = h * 64;
  const int qb0 = qt << 7;             // 128-row q tile
  const int qg = qb0 + w * 32 + l31;   // this lane's q row
  const int qend = qb0 + w * 32 + 31;  // wave's last q row
  const u16* Kbh = Kg + rb * 1024 + h64;
  const u16* VTbh = VTg + (size_t)bhid * 64 * 2048;  // [64 d][2048 t]
  const int srow = lane >> 3;
  const int schunk = ((lane & 7) ^ srow) * 8;

  // Q frags (B-operand): elem e of qf[kd] = Q[qg][kd*16 + 8*hi + e]
  bf16x8 qf[4];
#pragma unroll
  for (int kd = 0; kd < 4; ++kd)
    qf[kd] = *(const bf16x8*)(Qg + (rb + qg) * 1024 + h64 + kd * 16 + 8 * hi);

  f32x16 o0 = {}, o1 = {};               // o^T: d rows (+0/+32), q = l31
  const float MNEG = -30000.f;           // bounded sentinel; exp2 -> 0
  float lrun = 0.f;

  auto STAGE = [&](int it, int buf) {
    const int kv0 = it << 6;
    const int r0 = w * 16;
#pragma unroll
    for (int i = 0; i < 2; ++i) {
      gload_lds16(Kbh + (size_t)(kv0 + r0 + i * 8 + srow) * 1024 + schunk,
                  &Kt[buf][(r0 + i * 8) * 64]);
      gload_lds16(VTbh + (size_t)(r0 + i * 8 + srow) * 2048 + kv0 + schunk,
                  &Vt[buf][(r0 + i * 8) * 64]);
    }
  };
  STAGE(0, 0);
  asm volatile("s_waitcnt vmcnt(0)" ::: "memory");
  __syncthreads();

  const int nkv = 2 * qt + 2;
  for (int t = 0; t < nkv; ++t) {
    const int cur = t & 1;
    if (t + 1 < nkv) STAGE(t + 1, cur ^ 1);
    const int kv0 = t << 6;
    if (kv0 <= qend) {
      // ---- QK^T (s in log2 domain; Q pre-scaled by 0.125*log2e)
      f32x16 s0 = {}, s1 = {};
      __builtin_amdgcn_s_setprio(1);
#pragma unroll
      for (int kd = 0; kd < 4; ++kd) {
        const int col = (kd * 16 + 8 * hi) ^ ((l31 & 7) << 3);
        bf16x8 kf0 = *(const bf16x8*)&Kt[cur][l31 * 64 + col];
        bf16x8 kf1 = *(const bf16x8*)&Kt[cur][(32 + l31) * 64 + col];
        mfma32(s0, kf0, qf[kd]);
        mfma32(s1, kf1, qf[kd]);
      }
      __builtin_amdgcn_s_setprio(0);
      fence16x2(s0, s1);
      // ---- causal mask (diag-band iters only; bounded sentinel)
      if (kv0 + 63 > qb0 + w * 32) {
        const int lim = qg - (kv0 + 4 * hi);
#pragma unroll
        for (int r = 0; r < 16; ++r) {
          const int C0 = (r & 3) + 8 * (r >> 2);
          if (C0 > lim) s0[r] = MNEG;
          if (C0 + 32 > lim) s1[r] = MNEG;
        }
      }
      // ---- p = exp2(s) via raw v_exp_f32
#pragma unroll
      for (int r = 0; r < 16; ++r) {
        s0[r] = __builtin_amdgcn_exp2f(s0[r]);
        s1[r] = __builtin_amdgcn_exp2f(s1[r]);
      }
      // ---- row sum (explicit tree) + cross-half
      float t8[8];
#pragma unroll
      for (int r = 0; r < 8; ++r)
        t8[r] = (s0[2 * r] + s0[2 * r + 1]) + (s1[2 * r] + s1[2 * r + 1]);
      float rs = ((t8[0] + t8[1]) + (t8[2] + t8[3])) +
                 ((t8[4] + t8[5]) + (t8[6] + t8[7]));
      lrun += rs + __shfl_xor(rs, 32, 64);
      // ---- pack P into B-frags via permlane32_swap (flipped operand order)
      i32x4 paw[4];
#pragma unroll
      for (int tl = 0; tl < 2; ++tl) {
        const f32x16& p = tl ? s1 : s0;
#pragma unroll
        for (int ks = 0; ks < 2; ++ks) {
          unsigned pk0 = cvtpk(p[8 * ks + 0], p[8 * ks + 1]);
          unsigned pk1 = cvtpk(p[8 * ks + 2], p[8 * ks + 3]);
          unsigned pk2 = cvtpk(p[8 * ks + 4], p[8 * ks + 5]);
          unsigned pk3 = cvtpk(p[8 * ks + 6], p[8 * ks + 7]);
          asm("v_permlane32_swap_b32 %0, %1" : "+v"(pk0), "+v"(pk2));
          asm("v_permlane32_swap_b32 %0, %1" : "+v"(pk1), "+v"(pk3));
          i32x4 A;
          A[0] = (int)pk0;
          A[1] = (int)pk1;
          A[2] = (int)pk2;
          A[3] = (int)pk3;
          paw[tl * 2 + ks] = A;
        }
      }
      asm volatile("s_nop 1");
      // ---- PV: o^T += V^T-frag x P-frag
      __builtin_amdgcn_s_setprio(1);
#pragma unroll
      for (int tl = 0; tl < 2; ++tl)
#pragma unroll
        for (int ks = 0; ks < 2; ++ks) {
          bf16x8 pa = __builtin_bit_cast(bf16x8, paw[tl * 2 + ks]);
          const int kvc = tl * 32 + ks * 16 + 8 * hi;
#pragma unroll
          for (int dt = 0; dt < 2; ++dt) {
            const int row = dt * 32 + l31;
            bf16x8 vf = *(const bf16x8*)&Vt[cur][row * 64 + (kvc ^ ((l31 & 7) << 3))];
            if (dt == 0) mfma32(o0, vf, pa);
            else         mfma32(o1, vf, pa);
          }
        }
      __builtin_amdgcn_s_setprio(0);
    }
    asm volatile("s_waitcnt vmcnt(0)" ::: "memory");
    __syncthreads();
  }
  fence16x2(o0, o1);
  const float inv = 1.f / lrun;
  u16* Yrow = Yg + (rb + qg) * 1024 + h64;
#pragma unroll
  for (int r = 0; r < 16; r += 2) {
    const int dbase = (r & 3) + 8 * (r >> 2) + 4 * hi;
    *(unsigned*)(Yrow + dbase) = cvtpk(o0[r] * inv, o0[r + 1] * inv);
    *(unsigned*)(Yrow + 32 + dbase) = cvtpk(o1[r] * inv, o1[r + 1] * inv);
  }
}

// ---------------- launch ----------------
extern "C" void kernel_launch(void* const* d_in, const int* in_sizes, int n_in,
                              void* d_out, int out_size, void* d_ws, size_t ws_size,
                              hipStream_t stream) {
  const float* x = (const float*)d_in[0];
  char* ws = (char*)d_ws;
  u16* xb = (u16*)ws;                          // attention Y (bf16)
  u16* wb = (u16*)(ws + (16u << 20));          // 8 x 131072 bf16 weights
  u16* Rq = (u16*)(ws + (18u << 20));          // [8192][128]
  u16* Rk = (u16*)(ws + (20u << 20));
  u16* Rv = (u16*)(ws + (22u << 20));
  u16* Ry = (u16*)(ws + (24u << 20));
  u16* Qb = (u16*)(ws + (26u << 20));          // [8192][1024]
  u16* Kb = (u16*)(ws + (42u << 20));
  u16* VT = (u16*)(ws + (58u << 20));          // [64 bh][64 d][2048 t]
  const int WSZ = 131072;
  const float SC = 0.18033688011112042f;       // 0.125 * log2(e)

  W8 wp;
  for (int i = 0; i < 8; ++i) wp.s[i] = (const float*)d_in[1 + i];
  cvt_w_kernel<<<1024, 256, 0, stream>>>(wp, wb);

  // R_{q,k,v} = x @ {q,k,v}A^T (M=8192, N=128, K=1024), fp32 x converted
  // in-staging (CVTA), BM=64 -> 384 blocks
  G3 g1;
  g1.A[0] = g1.A[1] = g1.A[2] = (const u16*)x;
  g1.B[0] = wb; g1.B[1] = wb + 2 * WSZ; g1.B[2] = wb + 4 * WSZ;
  g1.C[0] = Rq; g1.C[1] = Rk; g1.C[2] = Rv;
  g1.osc[0] = g1.osc[1] = g1.osc[2] = 1.f;
  g1.vt[0] = g1.vt[1] = g1.vt[2] = 0;
  gemm_nt<u16, 64, true><<<dim3(128, 1, 3), 256, 0, stream>>>(g1, 8192, 128, 1024);

  // Q,K,V^T in ONE launch: Q scaled by SC; z=2 writes transposed V
  G3 g2;
  g2.A[0] = Rq; g2.A[1] = Rk; g2.A[2] = Rv;
  g2.B[0] = wb + 1 * WSZ; g2.B[1] = wb + 3 * WSZ; g2.B[2] = wb + 5 * WSZ;
  g2.C[0] = Qb; g2.C[1] = Kb; g2.C[2] = VT;
  g2.osc[0] = SC; g2.osc[1] = 1.f; g2.osc[2] = 1.f;
  g2.vt[0] = 0; g2.vt[1] = 0; g2.vt[2] = 1;
  gemm_nt<u16, 128, false><<<dim3(64, 8, 3), 256, 0, stream>>>(g2, 8192, 1024, 128);

  // Y (into xb) = causal attention
  attn_kernel<<<dim3(1024), 256, 0, stream>>>(Qb, Kb, VT, xb);

  // Ry = Y @ cA^T (BM=64 -> 128 blocks), out = Ry @ cB^T (fp32)
  G3 g3;
  g3.A[0] = g3.A[1] = g3.A[2] = xb;
  g3.B[0] = g3.B[1] = g3.B[2] = wb + 6 * WSZ;
  g3.C[0] = g3.C[1] = g3.C[2] = Ry;
  g3.osc[0] = g3.osc[1] = g3.osc[2] = 1.f;
  g3.vt[0] = g3.vt[1] = g3.vt[2] = 0;
  gemm_nt<u16, 64, false><<<dim3(128, 1, 1), 256, 0, stream>>>(g3, 8192, 128, 1024);
  G3 g4;
  g4.A[0] = g4.A[1] = g4.A[2] = Ry;
  g4.B[0] = g4.B[1] = g4.B[2] = wb + 7 * WSZ;
  g4.C[0] = g4.C[1] = g4.C[2] = d_out;
  g4.osc[0] = g4.osc[1] = g4.osc[2] = 1.f;
  g4.vt[0] = g4.vt[1] = g4.vt[2] = 0;
  gemm_nt<float, 128, false><<<dim3(64, 8, 1), 256, 0, stream>>>(g4, 8192, 1024, 128);
}